// Round 6
// baseline (293.917 us; speedup 1.0000x reference)
//
#include <hip/hip_runtime.h>
#include <hip/hip_bf16.h>

typedef __hip_bfloat16 bf16;
typedef float f32x4 __attribute__((ext_vector_type(4)));
typedef short s16x8 __attribute__((ext_vector_type(8)));

#define NN 8
#define HH 56
#define WW 56
#define C1 256
#define CM 128
#define C2 256
#define GG 4
#define K2K 9
#define HWSZ (HH*WW)            // 3136
#define LL (NN*HWSZ)            // 25088
#define EPSF 1e-5f
#define XP_H 58
#define XP_W 58

__device__ __forceinline__ float b2f(bf16 v){ return __bfloat162float(v); }

// ---------------- K0x: x NCHW f32 -> xp padded NHWC bf16, borders zeroed (fused) ----------------
__global__ __launch_bounds__(256) void k0x(const float* __restrict__ x, bf16* __restrict__ xp){
    __shared__ float lds[64][57];
    int bid = blockIdx.x;               // 8*58*4 = 1856
    int n = bid / 232; int rem = bid % 232;
    int yp = rem >> 2; int ci0 = (rem & 3) << 6;
    int tid = threadIdx.x;
    bool interior = (yp >= 1 && yp <= 56);
    if (interior){
        int y = yp - 1;
        for (int e = tid; e < 64*56; e += 256){
            int ci = e / 56, xx = e - (e/56)*56;
            lds[ci][xx] = x[((size_t)((n*C1 + ci0 + ci)*HH) + y)*WW + xx];
        }
        __syncthreads();
    }
    for (int g = tid; g < 464; g += 256){   // 58 px * 64 ch / 8
        int pxp = g >> 3, cig = (g & 7) << 3;
        s16x8 v;
        if (!interior || pxp == 0 || pxp == 57){
            #pragma unroll
            for (int j=0;j<8;j++) ((bf16*)&v)[j] = __float2bfloat16(0.f);
        } else {
            #pragma unroll
            for (int j=0;j<8;j++) ((bf16*)&v)[j] = __float2bfloat16(lds[cig+j][pxp-1]);
        }
        *(s16x8*)(xp + ((size_t)(n*XP_H + yp)*XP_W + pxp)*C1 + ci0 + cig) = v;
    }
}

// ---------------- K0wp: all weight repacks in one launch ----------------
// blocks [0,144): cv1 weights -> Wf B-frag layout: Wf[(kt*8+nt)*64+lane][j], k=tap*256+ci
// blocks [144,181): Wf2/Wf3/Wf4/scbi/wdwT
__global__ void k0wp(const float* __restrict__ w, const float* __restrict__ wout,
                     const float* __restrict__ winp, const float* __restrict__ woff,
                     const float* __restrict__ wmsk, const float* __restrict__ g2,
                     const float* __restrict__ bb2, const float* __restrict__ m2,
                     const float* __restrict__ v2, const float* __restrict__ bout,
                     const float* __restrict__ wdw,
                     bf16* __restrict__ Wf, bf16* __restrict__ Wf2, bf16* __restrict__ Wf3,
                     bf16* __restrict__ Wf4, float* __restrict__ scbi, float* __restrict__ wdwT){
    if (blockIdx.x < 144){
        int tlin = blockIdx.x*256 + threadIdx.x;   // 36864
        int kt  = tlin >> 9;
        int rem = tlin & 511;
        int nt  = rem >> 6;
        int lane = rem & 63;
        int co = nt*16 + (lane & 15);
        int kbase = kt*32 + (lane >> 4)*8;
        bf16* dst = Wf + (size_t)tlin*8;
        #pragma unroll
        for (int j = 0; j < 8; j++){
            int k = kbase + j;
            int tap = k >> 8;
            int ci  = k & 255;
            dst[j] = __float2bfloat16(w[((size_t)co*C1 + ci)*9 + tap]);
        }
        return;
    }
    int t = (blockIdx.x-144)*256 + threadIdx.x;     // 9344 used
    if (t < 4096){          // Wf2: A-frag wout^T
        int lane = t & 63; int kc = (t>>6)&3; int mt = t>>8;
        int co = mt*16 + (lane&15); int k0 = kc*32 + (lane>>4)*8;
        bf16* d = Wf2 + (size_t)t*8;
        #pragma unroll
        for (int j=0;j<8;j++) d[j] = __float2bfloat16(wout[(size_t)(k0+j)*C2 + co]);
    } else if (t < 6144){   // Wf3: B-frag winp
        int u = t - 4096; int lane = u&63; int kc=(u>>6)&3; int nt=u>>8;
        int co = nt*16+(lane&15); int k0 = kc*32+(lane>>4)*8;
        bf16* d = Wf3 + (size_t)u*8;
        #pragma unroll
        for (int j=0;j<8;j++) d[j] = __float2bfloat16(winp[(size_t)(k0+j)*CM + co]);
    } else if (t < 7936){   // Wf4: B-frag [woff|wmsk|0]
        int u = t - 6144; int lane=u&63; int kc=(u>>6)&3; int nt=u>>8;
        int nn2 = nt*16+(lane&15); int k0 = kc*32+(lane>>4)*8;
        bf16* d = Wf4 + (size_t)u*8;
        #pragma unroll
        for (int j=0;j<8;j++){
            int k = k0+j; float v = 0.f;
            if (nn2 < 72) v = woff[(size_t)k*72 + nn2];
            else if (nn2 < 108) v = wmsk[(size_t)k*36 + (nn2-72)];
            d[j] = __float2bfloat16(v);
        }
    } else if (t < 8192){
        int co = t - 7936;
        float sc = g2[co]*rsqrtf(v2[co]+EPSF);
        scbi[co] = sc;
        scbi[256+co] = bb2[co] - m2[co]*sc + bout[co]*sc;  // fold bout through BN2
    } else if (t < 8192 + 9*CM){
        int u = t - 8192;
        int tap = u >> 7, c = u & 127;
        wdwT[tap*CM + c] = wdw[c*9 + tap];
    }
}

// ---------------- K1: barrier-free implicit-GEMM conv via MFMA (M=64/block, wave=64x32) ----------------
__device__ __forceinline__ void loadA4(const bf16* __restrict__ xp, const long* abase, int s, s16x8* dst){
    int tap = s >> 3; int dy = tap/3, dx = tap - dy*3;
    int off = ((dy-1)*XP_W + (dx-1))*C1 + ((s&7)<<5);
    #pragma unroll
    for (int mi=0;mi<4;mi++) dst[mi] = *(const s16x8*)(xp + abase[mi] + off);
}
__device__ __forceinline__ void loadB2(const bf16* __restrict__ bbase, int s, s16x8* dst){
    #pragma unroll
    for (int j=0;j<2;j++) dst[j] = *(const s16x8*)(bbase + (size_t)s*4096 + j*512);
}

__global__ __launch_bounds__(256) void k1_mfma(
    const bf16* __restrict__ xp, const bf16* __restrict__ Wf,
    const float* __restrict__ bg, const float* __restrict__ bb,
    const float* __restrict__ bm, const float* __restrict__ bv,
    bf16* __restrict__ hb)
{
    int bid = blockIdx.x;              // 392 = 8*49
    int n = bid/49, p0 = (bid%49)*64;
    int tid = threadIdx.x, lane = tid & 63, w = tid >> 6;
    int col = lane & 15, kq = lane >> 4;
    long abase[4];
    #pragma unroll
    for (int mi=0;mi<4;mi++){
        int px = p0 + mi*16 + col;
        int y = px/WW, xx = px - (px/WW)*WW;
        abase[mi] = ((long)((n*XP_H + y + 1)*XP_W) + (xx+1))*C1 + kq*8;
    }
    const bf16* bbase = Wf + ((size_t)(w*2)*64 + lane)*8;

    f32x4 acc[4][2];
    #pragma unroll
    for (int mi=0;mi<4;mi++)
        #pragma unroll
        for (int nj=0;nj<2;nj++) acc[mi][nj] = (f32x4){0,0,0,0};

    s16x8 A0[4], B0[2], A1[4], B1[2];
    loadA4(xp, abase, 0, A0); loadB2(bbase, 0, B0);
    #pragma unroll
    for (int s=0; s<72; s++){
        s16x8* Ac = (s&1) ? A1 : A0;
        s16x8* Bc = (s&1) ? B1 : B0;
        s16x8* An = (s&1) ? A0 : A1;
        s16x8* Bn = (s&1) ? B0 : B1;
        if (s+1 < 72){ loadA4(xp, abase, s+1, An); loadB2(bbase, s+1, Bn); }
        #pragma unroll
        for (int mi=0;mi<4;mi++)
            #pragma unroll
            for (int nj=0;nj<2;nj++)
                acc[mi][nj] = __builtin_amdgcn_mfma_f32_16x16x32_bf16(Ac[mi], Bc[nj], acc[mi][nj], 0, 0, 0);
    }

    // epilogue: C layout col=lane&15 -> co, row=kq*4+r -> px
    #pragma unroll
    for (int nj=0;nj<2;nj++){
        int co = w*32 + nj*16 + col;
        float sc = bg[co] * rsqrtf(bv[co] + EPSF);
        float bi = bb[co] - bm[co]*sc;
        #pragma unroll
        for (int mi=0;mi<4;mi++){
            #pragma unroll
            for (int r=0;r<4;r++){
                int px = p0 + mi*16 + kq*4 + r;
                float z = acc[mi][nj][r]*sc + bi;
                float sl = z / (1.f + expf(-z));
                hb[((size_t)n*HWSZ + px)*CM + co] = __float2bfloat16(sl);
            }
        }
    }
}

// ---------------- K3f: dw3x3+LN+GELU (fused k2) + MFMA GEMMs val/om ----------------
__global__ __launch_bounds__(256) void k3f(
    const bf16* __restrict__ hb,
    const float* __restrict__ wdwT, const float* __restrict__ bdw,
    const float* __restrict__ lng, const float* __restrict__ lnb,
    const bf16* __restrict__ Wf3, const bf16* __restrict__ Wf4,
    const float* __restrict__ binp, const float* __restrict__ boff, const float* __restrict__ bmsk,
    bf16* __restrict__ val, float* __restrict__ om)
{
    __shared__ __align__(16) bf16 Ah[64*136];
    __shared__ __align__(16) bf16 At[64*136];
    int blk = blockIdx.x;               // 392
    int n = blk/49; int p0 = (blk%49)*64;
    size_t pixbase = (size_t)n*HWSZ + p0;
    int tid = threadIdx.x;
    // phase 1: stage Ah (hb tile for GEMM1)
    for (int e = tid; e < 1024; e += 256){
        int row = e>>4, seg = e&15;
        *(s16x8*)&Ah[row*136 + seg*8] = *(const s16x8*)(hb + (pixbase+row)*CM + seg*8);
    }
    // phase 2: depthwise + LN + GELU -> At (no barrier needed vs phase1: disjoint LDS)
    {
        int slot = tid & 15, c0 = slot*8;
        int pbase = (tid >> 4) * 4;
        const bf16* hbase = hb + (size_t)n*HWSZ*CM;
        float4 b0 = *(const float4*)(bdw + c0);
        float4 b1 = *(const float4*)(bdw + c0 + 4);
        float4 g0 = *(const float4*)(lng + c0); float4 g1 = *(const float4*)(lng + c0+4);
        float4 q0 = *(const float4*)(lnb + c0); float4 q1 = *(const float4*)(lnb + c0+4);
        float gv[8]={g0.x,g0.y,g0.z,g0.w,g1.x,g1.y,g1.z,g1.w};
        float qv[8]={q0.x,q0.y,q0.z,q0.w,q1.x,q1.y,q1.z,q1.w};
        #pragma unroll
        for (int i=0;i<4;i++){
            int pxl = p0 + pbase + i;
            int y = pxl/WW, xq = pxl - (pxl/WW)*WW;
            float acc[8] = {b0.x,b0.y,b0.z,b0.w,b1.x,b1.y,b1.z,b1.w};
            #pragma unroll
            for (int tap=0; tap<9; tap++){
                int dy=tap/3, dx=tap%3;
                int yy=y+dy-1, xx=xq+dx-1;
                if ((unsigned)yy < HH && (unsigned)xx < WW){
                    s16x8 v = *(const s16x8*)(hbase + ((size_t)(yy*WW+xx))*CM + c0);
                    float4 w0 = *(const float4*)(wdwT + tap*CM + c0);
                    float4 w1 = *(const float4*)(wdwT + tap*CM + c0 + 4);
                    float wv[8] = {w0.x,w0.y,w0.z,w0.w,w1.x,w1.y,w1.z,w1.w};
                    #pragma unroll
                    for (int j=0;j<8;j++) acc[j] += b2f(((bf16*)&v)[j]) * wv[j];
                }
            }
            float s1=0.f, s2=0.f;
            #pragma unroll
            for (int j=0;j<8;j++){ s1 += acc[j]; s2 += acc[j]*acc[j]; }
            #pragma unroll
            for (int off=1; off<16; off<<=1){
                s1 += __shfl_xor(s1, off);
                s2 += __shfl_xor(s2, off);
            }
            float mean = s1*(1.f/CM);
            float var  = fmaxf(s2*(1.f/CM) - mean*mean, 0.f);
            float inv  = rsqrtf(var + EPSF);
            s16x8 ov;
            #pragma unroll
            for (int j=0;j<8;j++){
                float z = (acc[j]-mean)*inv*gv[j] + qv[j];
                float gl = 0.5f*z*(1.f + erff(z*0.70710678118654752f));
                ((bf16*)&ov)[j] = __float2bfloat16(gl);
            }
            *(s16x8*)&At[(pbase+i)*136 + c0] = ov;
        }
    }
    __syncthreads();
    // phase 3: GEMMs
    int lane = tid & 63, w = tid >> 6;
    int col = lane & 15, kq = lane >> 4;
    s16x8 a0[4], a1[4];
    #pragma unroll
    for (int kc=0;kc<4;kc++){
        a0[kc] = *(const s16x8*)&Ah[(w*16+col)*136 + kc*32 + kq*8];
        a1[kc] = *(const s16x8*)&At[(w*16+col)*136 + kc*32 + kq*8];
    }
    int pxo = p0 + w*16 + kq*4;
    #pragma unroll
    for (int nt=0; nt<8; nt++){
        f32x4 acc = {0,0,0,0};
        #pragma unroll
        for (int kc=0;kc<4;kc++){
            s16x8 b = *(const s16x8*)(Wf3 + ((size_t)(nt*4+kc)*64 + lane)*8);
            acc = __builtin_amdgcn_mfma_f32_16x16x32_bf16(a0[kc], b, acc, 0, 0, 0);
        }
        int co = nt*16 + col;
        float bia = binp[co];
        #pragma unroll
        for (int r=0;r<4;r++)
            val[((size_t)n*HWSZ + pxo + r)*CM + co] = __float2bfloat16(acc[r] + bia);
    }
    #pragma unroll
    for (int nt=0; nt<7; nt++){
        f32x4 acc = {0,0,0,0};
        #pragma unroll
        for (int kc=0;kc<4;kc++){
            s16x8 b = *(const s16x8*)(Wf4 + ((size_t)(nt*4+kc)*64 + lane)*8);
            acc = __builtin_amdgcn_mfma_f32_16x16x32_bf16(a1[kc], b, acc, 0, 0, 0);
        }
        int nn2 = nt*16 + col;
        float bia = (nn2<72) ? boff[nn2] : (nn2<108 ? bmsk[nn2-72] : 0.f);
        #pragma unroll
        for (int r=0;r<4;r++)
            om[((size_t)n*HWSZ + pxo + r)*112 + nn2] = acc[r] + bia;
    }
}

// ---------------- K4f: softmax + gather (into LDS) + output-proj MFMA + BN2 + SiLU + residual ----------------
__global__ __launch_bounds__(256) void k4f(
    const bf16* __restrict__ valb, const float* __restrict__ om,
    const bf16* __restrict__ Wf2, const float* __restrict__ scbi,
    const float* __restrict__ xin, float* __restrict__ out)
{
    __shared__ float omb[64][112];
    __shared__ float mk[64][36];
    __shared__ __align__(16) bf16 Bl[64*136];
    int blk = blockIdx.x;               // 392
    int n = blk/49; int p0 = (blk%49)*64;
    size_t pixg0 = (size_t)n*HWSZ + p0;
    int tid = threadIdx.x;
    // phase 1: stage om
    for (int e = tid; e < 1792; e += 256){
        int p = e/28, q = e - (e/28)*28;
        *(float4*)&omb[p][q*4] = *(const float4*)(om + (pixg0+p)*112 + q*4);
    }
    __syncthreads();
    // phase 2: softmax (64 px * 4 groups = 256 tasks)
    {
        int p = tid >> 2, g = tid & 3;
        float mx = omb[p][72+g*9];
        #pragma unroll
        for (int j=1;j<9;j++) mx = fmaxf(mx, omb[p][72+g*9+j]);
        float sum=0.f; float e9[9];
        #pragma unroll
        for (int j=0;j<9;j++){ e9[j] = expf(omb[p][72+g*9+j]-mx); sum += e9[j]; }
        float inv = 1.f/sum;
        #pragma unroll
        for (int j=0;j<9;j++) mk[p][g*9+j] = e9[j]*inv;
    }
    __syncthreads();
    // phase 3: gather, 4 px per thread, 8 ch each
    {
        int slot = tid & 15, c0 = slot*8, g = slot >> 2;
        int pbase = (tid >> 4) * 4;
        const bf16* vb = valb + (size_t)n*HWSZ*CM;
        #pragma unroll
        for (int i=0;i<4;i++){
            int p = pbase + i;
            int pxl = p0 + p;
            int y = pxl/WW, xq = pxl - (pxl/WW)*WW;
            float acc[8] = {0,0,0,0,0,0,0,0};
            #pragma unroll
            for (int k=0;k<9;k++){
                float oxv = omb[p][g*18 + k*2];
                float oyv = omb[p][g*18 + k*2 + 1];
                float sx = (float)xq + (float)(k/3) - 1.f + oxv;
                float sy = (float)y  + (float)(k%3) - 1.f + oyv;
                float x0f = floorf(sx), y0f = floorf(sy);
                float fx = sx - x0f, fy = sy - y0f;
                int x0 = (int)x0f, y0 = (int)y0f;
                float mw = mk[p][g*9+k];
                float w00 = (1.f-fy)*(1.f-fx)*mw;
                float w01 = (1.f-fy)*fx*mw;
                float w10 = fy*(1.f-fx)*mw;
                float w11 = fy*fx*mw;
                if ((unsigned)y0 < HH && (unsigned)x0 < WW){
                    s16x8 v = *(const s16x8*)(vb + ((size_t)(y0*WW+x0))*CM + c0);
                    #pragma unroll
                    for (int j=0;j<8;j++) acc[j] += w00*b2f(((bf16*)&v)[j]);
                }
                if ((unsigned)y0 < HH && (unsigned)(x0+1) < WW){
                    s16x8 v = *(const s16x8*)(vb + ((size_t)(y0*WW+x0+1))*CM + c0);
                    #pragma unroll
                    for (int j=0;j<8;j++) acc[j] += w01*b2f(((bf16*)&v)[j]);
                }
                if ((unsigned)(y0+1) < HH && (unsigned)x0 < WW){
                    s16x8 v = *(const s16x8*)(vb + ((size_t)((y0+1)*WW+x0))*CM + c0);
                    #pragma unroll
                    for (int j=0;j<8;j++) acc[j] += w10*b2f(((bf16*)&v)[j]);
                }
                if ((unsigned)(y0+1) < HH && (unsigned)(x0+1) < WW){
                    s16x8 v = *(const s16x8*)(vb + ((size_t)((y0+1)*WW+x0+1))*CM + c0);
                    #pragma unroll
                    for (int j=0;j<8;j++) acc[j] += w11*b2f(((bf16*)&v)[j]);
                }
            }
            s16x8 ov;
            #pragma unroll
            for (int j=0;j<8;j++) ((bf16*)&ov)[j] = __float2bfloat16(acc[j]);
            *(s16x8*)&Bl[p*136 + c0] = ov;
        }
    }
    __syncthreads();
    // phase 4: output proj MFMA + BN2 + SiLU + residual
    int lane = tid & 63, w = tid >> 6;
    int col = lane & 15, kq = lane >> 4;
    int co0 = w*64;
    s16x8 af[4][4];
    #pragma unroll
    for (int mt=0;mt<4;mt++)
        #pragma unroll
        for (int kc=0;kc<4;kc++)
            af[mt][kc] = *(const s16x8*)(Wf2 + (((size_t)((co0>>4)+mt)*4 + kc)*64 + lane)*8);
    f32x4 acc[4][4];
    #pragma unroll
    for (int mt=0;mt<4;mt++)
        #pragma unroll
        for (int nt=0;nt<4;nt++)
            acc[mt][nt] = (f32x4){0,0,0,0};
    #pragma unroll
    for (int nt=0;nt<4;nt++){
        s16x8 bfr[4];
        #pragma unroll
        for (int kc=0;kc<4;kc++)
            bfr[kc] = *(const s16x8*)&Bl[(nt*16+col)*136 + kc*32 + kq*8];
        #pragma unroll
        for (int mt=0;mt<4;mt++)
            #pragma unroll
            for (int kc=0;kc<4;kc++)
                acc[mt][nt] = __builtin_amdgcn_mfma_f32_16x16x32_bf16(af[mt][kc], bfr[kc], acc[mt][nt], 0, 0, 0);
    }
    #pragma unroll
    for (int mt=0;mt<4;mt++){
        #pragma unroll
        for (int r=0;r<4;r++){
            int co = co0 + mt*16 + kq*4 + r;
            float sc = scbi[co], bi = scbi[256+co];
            #pragma unroll
            for (int nt=0;nt<4;nt++){
                int px = p0 + nt*16 + col;
                size_t idx = ((size_t)(n*C2 + co))*HWSZ + px;
                float z = acc[mt][nt][r]*sc + bi;
                float sl = z/(1.f+expf(-z));
                out[idx] = sl + xin[idx];
            }
        }
    }
}

extern "C" void kernel_launch(void* const* d_in, const int* in_sizes, int n_in,
                              void* d_out, int out_size, void* d_ws, size_t ws_size,
                              hipStream_t stream)
{
    const float* x    = (const float*)d_in[0];
    const float* wcv1 = (const float*)d_in[1];
    const float* bn1g = (const float*)d_in[2];
    const float* bn1b = (const float*)d_in[3];
    const float* bn1m = (const float*)d_in[4];
    const float* bn1v = (const float*)d_in[5];
    const float* wdw  = (const float*)d_in[6];
    const float* bdw  = (const float*)d_in[7];
    const float* lng  = (const float*)d_in[8];
    const float* lnb  = (const float*)d_in[9];
    const float* winp = (const float*)d_in[10];
    const float* binp = (const float*)d_in[11];
    const float* woff = (const float*)d_in[12];
    const float* boff = (const float*)d_in[13];
    const float* wmsk = (const float*)d_in[14];
    const float* bmsk = (const float*)d_in[15];
    const float* wout = (const float*)d_in[16];
    const float* bout = (const float*)d_in[17];
    const float* bn2g = (const float*)d_in[18];
    const float* bn2b = (const float*)d_in[19];
    const float* bn2m = (const float*)d_in[20];
    const float* bn2v = (const float*)d_in[21];

    unsigned char* base = (unsigned char*)d_ws;
    bf16*  Wf   = (bf16*)(base);                    //         0 +   589,824
    bf16*  Wf2  = (bf16*)(base + 589824);           //    65,536
    bf16*  Wf3  = (bf16*)(base + 655360);           //    32,768
    bf16*  Wf4  = (bf16*)(base + 688128);           //    28,672
    float* scbi = (float*)(base + 716800);          //     2,048
    float* wdwT = (float*)(base + 718848);          //     4,608
    bf16*  xp   = (bf16*)(base + 723456);           // 13,778,944 (dead after k1; val aliases)
    bf16*  val  = (bf16*)(base + 723456);           //  6,422,528 (inside old xp region)
    bf16*  hb   = (bf16*)(base + 14502400);         //  6,422,528
    float* om   = (float*)(base + 20924928);        // 11,239,424 (end 32,164,352)

    hipLaunchKernelGGL(k0x, dim3(NN*XP_H*4), dim3(256), 0, stream, x, xp);
    hipLaunchKernelGGL(k0wp, dim3(181), dim3(256), 0, stream,
                       wcv1, wout, winp, woff, wmsk, bn2g, bn2b, bn2m, bn2v, bout, wdw,
                       Wf, Wf2, Wf3, Wf4, scbi, wdwT);
    hipLaunchKernelGGL(k1_mfma, dim3(NN*49), dim3(256), 0, stream,
                       xp, Wf, bn1g, bn1b, bn1m, bn1v, hb);
    hipLaunchKernelGGL(k3f, dim3(NN*49), dim3(256), 0, stream,
                       hb, wdwT, bdw, lng, lnb, Wf3, Wf4, binp, boff, bmsk, val, om);
    hipLaunchKernelGGL(k4f, dim3(NN*49), dim3(256), 0, stream,
                       val, om, Wf2, scbi, x, (float*)d_out);
}

// Round 7
// 273.568 us; speedup vs baseline: 1.0744x; 1.0744x over previous
//
#include <hip/hip_runtime.h>
#include <hip/hip_bf16.h>

typedef __hip_bfloat16 bf16;
typedef float f32x4 __attribute__((ext_vector_type(4)));
typedef short s16x8 __attribute__((ext_vector_type(8)));

#define NN 8
#define HH 56
#define WW 56
#define C1 256
#define CM 128
#define C2 256
#define GG 4
#define K2K 9
#define HWSZ (HH*WW)            // 3136
#define LL (NN*HWSZ)            // 25088
#define EPSF 1e-5f
#define XP_H 58
#define XP_W 58

__device__ __forceinline__ float b2f(bf16 v){ return __bfloat162float(v); }

// ---------------- K0x: x NCHW f32 -> xp padded NHWC bf16, borders zeroed ----------------
__global__ __launch_bounds__(256) void k0x(const float* __restrict__ x, bf16* __restrict__ xp){
    __shared__ float lds[64][57];
    int bid = blockIdx.x;               // 8*58*4 = 1856
    int n = bid / 232; int rem = bid % 232;
    int yp = rem >> 2; int ci0 = (rem & 3) << 6;
    int tid = threadIdx.x;
    bool interior = (yp >= 1 && yp <= 56);
    if (interior){
        int y = yp - 1;
        for (int e = tid; e < 64*56; e += 256){
            int ci = e / 56, xx = e - (e/56)*56;
            lds[ci][xx] = x[((size_t)((n*C1 + ci0 + ci)*HH) + y)*WW + xx];
        }
        __syncthreads();
    }
    for (int g = tid; g < 464; g += 256){
        int pxp = g >> 3, cig = (g & 7) << 3;
        s16x8 v;
        if (!interior || pxp == 0 || pxp == 57){
            #pragma unroll
            for (int j=0;j<8;j++) ((bf16*)&v)[j] = __float2bfloat16(0.f);
        } else {
            #pragma unroll
            for (int j=0;j<8;j++) ((bf16*)&v)[j] = __float2bfloat16(lds[cig+j][pxp-1]);
        }
        *(s16x8*)(xp + ((size_t)(n*XP_H + yp)*XP_W + pxp)*C1 + ci0 + cig) = v;
    }
}

// ---------------- K0wp: all weight repacks in one launch ----------------
__global__ void k0wp(const float* __restrict__ w, const float* __restrict__ wout,
                     const float* __restrict__ winp, const float* __restrict__ woff,
                     const float* __restrict__ wmsk, const float* __restrict__ g2,
                     const float* __restrict__ bb2, const float* __restrict__ m2,
                     const float* __restrict__ v2, const float* __restrict__ bout,
                     const float* __restrict__ wdw,
                     bf16* __restrict__ Wf, bf16* __restrict__ Wf2, bf16* __restrict__ Wf3,
                     bf16* __restrict__ Wf4, float* __restrict__ scbi, float* __restrict__ wdwT){
    if (blockIdx.x < 144){
        int tlin = blockIdx.x*256 + threadIdx.x;   // 36864
        int kt  = tlin >> 9;
        int rem = tlin & 511;
        int nt  = rem >> 6;
        int lane = rem & 63;
        int co = nt*16 + (lane & 15);
        int kbase = kt*32 + (lane >> 4)*8;
        bf16* dst = Wf + (size_t)tlin*8;
        #pragma unroll
        for (int j = 0; j < 8; j++){
            int k = kbase + j;
            int tap = k >> 8;
            int ci  = k & 255;
            dst[j] = __float2bfloat16(w[((size_t)co*C1 + ci)*9 + tap]);
        }
        return;
    }
    int t = (blockIdx.x-144)*256 + threadIdx.x;
    if (t < 4096){          // Wf2: A-frag wout^T
        int lane = t & 63; int kc = (t>>6)&3; int mt = t>>8;
        int co = mt*16 + (lane&15); int k0 = kc*32 + (lane>>4)*8;
        bf16* d = Wf2 + (size_t)t*8;
        #pragma unroll
        for (int j=0;j<8;j++) d[j] = __float2bfloat16(wout[(size_t)(k0+j)*C2 + co]);
    } else if (t < 6144){   // Wf3: B-frag winp
        int u = t - 4096; int lane = u&63; int kc=(u>>6)&3; int nt=u>>8;
        int co = nt*16+(lane&15); int k0 = kc*32+(lane>>4)*8;
        bf16* d = Wf3 + (size_t)u*8;
        #pragma unroll
        for (int j=0;j<8;j++) d[j] = __float2bfloat16(winp[(size_t)(k0+j)*CM + co]);
    } else if (t < 7936){   // Wf4: B-frag [woff|wmsk|0]
        int u = t - 6144; int lane=u&63; int kc=(u>>6)&3; int nt=u>>8;
        int nn2 = nt*16+(lane&15); int k0 = kc*32+(lane>>4)*8;
        bf16* d = Wf4 + (size_t)u*8;
        #pragma unroll
        for (int j=0;j<8;j++){
            int k = k0+j; float v = 0.f;
            if (nn2 < 72) v = woff[(size_t)k*72 + nn2];
            else if (nn2 < 108) v = wmsk[(size_t)k*36 + (nn2-72)];
            d[j] = __float2bfloat16(v);
        }
    } else if (t < 8192){
        int co = t - 7936;
        float sc = g2[co]*rsqrtf(v2[co]+EPSF);
        scbi[co] = sc;
        scbi[256+co] = bb2[co] - m2[co]*sc + bout[co]*sc;
    } else if (t < 8192 + 9*CM){
        int u = t - 8192;
        int tap = u >> 7, c = u & 127;
        wdwT[tap*CM + c] = wdw[c*9 + tap];
    }
}

// ---------------- K1: barrier-free MFMA conv, M=32/block (784 blocks), depth-2 prefetch ----------------
__device__ __forceinline__ void loadA2(const bf16* __restrict__ xp, const long* abase, int s, s16x8* dst){
    int tap = s >> 3; int dy = tap/3, dx = tap - dy*3;
    int off = ((dy-1)*XP_W + (dx-1))*C1 + ((s&7)<<5);
    #pragma unroll
    for (int mi=0;mi<2;mi++) dst[mi] = *(const s16x8*)(xp + abase[mi] + off);
}
__device__ __forceinline__ void loadB2(const bf16* __restrict__ bbase, int s, s16x8* dst){
    #pragma unroll
    for (int j=0;j<2;j++) dst[j] = *(const s16x8*)(bbase + (size_t)s*4096 + j*512);
}

__global__ __launch_bounds__(256) void k1_mfma(
    const bf16* __restrict__ xp, const bf16* __restrict__ Wf,
    const float* __restrict__ bg, const float* __restrict__ bb,
    const float* __restrict__ bm, const float* __restrict__ bv,
    bf16* __restrict__ hb)
{
    int bid = blockIdx.x;              // 784 = 8*98
    int n = bid/98, p0 = (bid%98)*32;
    int tid = threadIdx.x, lane = tid & 63, w = tid >> 6;   // w = co-quarter
    int col = lane & 15, kq = lane >> 4;
    long abase[2];
    #pragma unroll
    for (int mi=0;mi<2;mi++){
        int px = p0 + mi*16 + col;
        int y = px/WW, xx = px - (px/WW)*WW;
        abase[mi] = ((long)((n*XP_H + y + 1)*XP_W) + (xx+1))*C1 + kq*8;
    }
    const bf16* bbase = Wf + ((size_t)(w*2)*64 + lane)*8;   // nt = 2w, 2w+1

    f32x4 acc[2][2];
    #pragma unroll
    for (int mi=0;mi<2;mi++)
        #pragma unroll
        for (int nj=0;nj<2;nj++) acc[mi][nj] = (f32x4){0,0,0,0};

    s16x8 Ab[3][2], Bb[3][2];
    loadA2(xp, abase, 0, Ab[0]); loadB2(bbase, 0, Bb[0]);
    loadA2(xp, abase, 1, Ab[1]); loadB2(bbase, 1, Bb[1]);
    #pragma unroll
    for (int s=0; s<72; s++){
        int cur = s % 3, nxt = (s+2) % 3;
        if (s+2 < 72){ loadA2(xp, abase, s+2, Ab[nxt]); loadB2(bbase, s+2, Bb[nxt]); }
        #pragma unroll
        for (int mi=0;mi<2;mi++)
            #pragma unroll
            for (int nj=0;nj<2;nj++)
                acc[mi][nj] = __builtin_amdgcn_mfma_f32_16x16x32_bf16(Ab[cur][mi], Bb[cur][nj], acc[mi][nj], 0, 0, 0);
    }

    // epilogue: col -> co (N), kq*4+r -> px (M)
    #pragma unroll
    for (int nj=0;nj<2;nj++){
        int co = w*32 + nj*16 + col;
        float sc = bg[co] * rsqrtf(bv[co] + EPSF);
        float bi = bb[co] - bm[co]*sc;
        #pragma unroll
        for (int mi=0;mi<2;mi++){
            #pragma unroll
            for (int r=0;r<4;r++){
                int px = p0 + mi*16 + kq*4 + r;
                float z = acc[mi][nj][r]*sc + bi;
                float sl = z / (1.f + expf(-z));
                hb[((size_t)n*HWSZ + px)*CM + co] = __float2bfloat16(sl);
            }
        }
    }
}

// ---------------- K2: depthwise 3x3 + LN + GELU, 8 pixels/block, 16B loads ----------------
__global__ __launch_bounds__(128) void k2v(
    const bf16* __restrict__ hb, const float* __restrict__ wdwT, const float* __restrict__ bdw,
    const float* __restrict__ lng, const float* __restrict__ lnb, bf16* __restrict__ tb)
{
    int t = threadIdx.x;
    int p = t >> 4, s = t & 15;
    int pix = blockIdx.x*8 + p;
    int n = pix / HWSZ, rem = pix % HWSZ;
    int y = rem / WW, xq = rem % WW;
    int c0 = s*8;
    const bf16* hbase = hb + (size_t)n*HWSZ*CM;
    float acc[8];
    {
        float4 b0 = *(const float4*)(bdw + c0);
        float4 b1 = *(const float4*)(bdw + c0 + 4);
        acc[0]=b0.x; acc[1]=b0.y; acc[2]=b0.z; acc[3]=b0.w;
        acc[4]=b1.x; acc[5]=b1.y; acc[6]=b1.z; acc[7]=b1.w;
    }
    #pragma unroll
    for (int tap=0; tap<9; tap++){
        int dy=tap/3, dx=tap%3;
        int yy=y+dy-1, xx=xq+dx-1;
        if ((unsigned)yy < HH && (unsigned)xx < WW){
            s16x8 v = *(const s16x8*)(hbase + ((size_t)(yy*WW+xx))*CM + c0);
            float4 w0 = *(const float4*)(wdwT + tap*CM + c0);
            float4 w1 = *(const float4*)(wdwT + tap*CM + c0 + 4);
            float wv[8] = {w0.x,w0.y,w0.z,w0.w,w1.x,w1.y,w1.z,w1.w};
            #pragma unroll
            for (int j=0;j<8;j++)
                acc[j] += b2f(((bf16*)&v)[j]) * wv[j];
        }
    }
    float s1=0.f, s2=0.f;
    #pragma unroll
    for (int j=0;j<8;j++){ s1 += acc[j]; s2 += acc[j]*acc[j]; }
    #pragma unroll
    for (int off=1; off<16; off<<=1){
        s1 += __shfl_xor(s1, off);
        s2 += __shfl_xor(s2, off);
    }
    float mean = s1*(1.f/CM);
    float var  = fmaxf(s2*(1.f/CM) - mean*mean, 0.f);
    float inv  = rsqrtf(var + EPSF);
    float4 g0 = *(const float4*)(lng + c0); float4 g1 = *(const float4*)(lng + c0+4);
    float4 q0 = *(const float4*)(lnb + c0); float4 q1 = *(const float4*)(lnb + c0+4);
    float gv[8]={g0.x,g0.y,g0.z,g0.w,g1.x,g1.y,g1.z,g1.w};
    float qv[8]={q0.x,q0.y,q0.z,q0.w,q1.x,q1.y,q1.z,q1.w};
    s16x8 ov;
    #pragma unroll
    for (int j=0;j<8;j++){
        float z = (acc[j]-mean)*inv*gv[j] + qv[j];
        float gl = 0.5f*z*(1.f + erff(z*0.70710678118654752f));
        ((bf16*)&ov)[j] = __float2bfloat16(gl);
    }
    *(s16x8*)(tb + (size_t)pix*CM + c0) = ov;
}

// ---------------- K3: MFMA GEMMs: val = hb x Winp (+binp), om = tb x [Woff|Wmsk] (+bias) ----------------
__global__ __launch_bounds__(256) void k3_gemm(
    const bf16* __restrict__ hb, const bf16* __restrict__ tb,
    const bf16* __restrict__ Wf3, const bf16* __restrict__ Wf4,
    const float* __restrict__ binp, const float* __restrict__ boff, const float* __restrict__ bmsk,
    bf16* __restrict__ val, float* __restrict__ om)
{
    __shared__ __align__(16) bf16 Ah[64*136];
    __shared__ __align__(16) bf16 At[64*136];
    int blk = blockIdx.x;
    int n = blk/49; int p0 = (blk%49)*64;
    size_t pixbase = (size_t)n*HWSZ + p0;
    int tid = threadIdx.x;
    for (int e = tid; e < 1024; e += 256){
        int row = e>>4, seg = e&15;
        *(s16x8*)&Ah[row*136 + seg*8] = *(const s16x8*)(hb + (pixbase+row)*CM + seg*8);
        *(s16x8*)&At[row*136 + seg*8] = *(const s16x8*)(tb + (pixbase+row)*CM + seg*8);
    }
    __syncthreads();
    int lane = tid & 63, w = tid >> 6;
    int col = lane & 15, kq = lane >> 4;
    int mt = w;
    s16x8 a0[4], a1[4];
    #pragma unroll
    for (int kc=0;kc<4;kc++){
        a0[kc] = *(const s16x8*)&Ah[(mt*16+col)*136 + kc*32 + kq*8];
        a1[kc] = *(const s16x8*)&At[(mt*16+col)*136 + kc*32 + kq*8];
    }
    int pxo = p0 + mt*16 + kq*4;
    #pragma unroll
    for (int nt=0; nt<8; nt++){
        f32x4 acc = {0,0,0,0};
        #pragma unroll
        for (int kc=0;kc<4;kc++){
            s16x8 b = *(const s16x8*)(Wf3 + ((size_t)(nt*4+kc)*64 + lane)*8);
            acc = __builtin_amdgcn_mfma_f32_16x16x32_bf16(a0[kc], b, acc, 0, 0, 0);
        }
        int co = nt*16 + col;
        float bia = binp[co];
        #pragma unroll
        for (int r=0;r<4;r++)
            val[((size_t)n*HWSZ + pxo + r)*CM + co] = __float2bfloat16(acc[r] + bia);
    }
    #pragma unroll
    for (int nt=0; nt<7; nt++){
        f32x4 acc = {0,0,0,0};
        #pragma unroll
        for (int kc=0;kc<4;kc++){
            s16x8 b = *(const s16x8*)(Wf4 + ((size_t)(nt*4+kc)*64 + lane)*8);
            acc = __builtin_amdgcn_mfma_f32_16x16x32_bf16(a1[kc], b, acc, 0, 0, 0);
        }
        int nn2 = nt*16 + col;
        float bia = (nn2<72) ? boff[nn2] : (nn2<108 ? bmsk[nn2-72] : 0.f);
        #pragma unroll
        for (int r=0;r<4;r++)
            om[((size_t)n*HWSZ + pxo + r)*112 + nn2] = acc[r] + bia;
    }
}

// ---------------- K4a: softmax + DCNv3 bilinear gather, 8 pixels/block, 16B loads ----------------
__global__ __launch_bounds__(128) void k4a(
    const bf16* __restrict__ valb, const float* __restrict__ om, bf16* __restrict__ o)
{
    __shared__ float omb[8][112];
    __shared__ float mk[8][36];
    int t = threadIdx.x;
    int pix0 = blockIdx.x*8;
    for (int e = t; e < 8*112; e += 128){
        int p = e / 112, q = e - (e/112)*112;
        omb[p][q] = om[(size_t)(pix0+p)*112 + q];
    }
    __syncthreads();
    if (t < 32){
        int p = t >> 2, g = t & 3;
        float mx = omb[p][72+g*9];
        #pragma unroll
        for (int j=1;j<9;j++) mx = fmaxf(mx, omb[p][72+g*9+j]);
        float sum=0.f; float e9[9];
        #pragma unroll
        for (int j=0;j<9;j++){ e9[j] = expf(omb[p][72+g*9+j]-mx); sum += e9[j]; }
        float inv = 1.f/sum;
        #pragma unroll
        for (int j=0;j<9;j++) mk[p][g*9+j] = e9[j]*inv;
    }
    __syncthreads();
    int p = t >> 4, s = t & 15;
    int g = s >> 2;
    int c0 = s*8;
    int pix = pix0 + p;
    int n = pix / HWSZ, rem = pix % HWSZ;
    int y = rem / WW, xq = rem % WW;
    const bf16* vb = valb + (size_t)n*HWSZ*CM;
    float acc[8] = {0,0,0,0,0,0,0,0};
    #pragma unroll
    for (int k=0;k<9;k++){
        float oxv = omb[p][g*18 + k*2];
        float oyv = omb[p][g*18 + k*2 + 1];
        float sx = (float)xq + (float)(k/3) - 1.f + oxv;
        float sy = (float)y  + (float)(k%3) - 1.f + oyv;
        float x0f = floorf(sx), y0f = floorf(sy);
        float fx = sx - x0f, fy = sy - y0f;
        int x0 = (int)x0f, y0 = (int)y0f;
        float mw = mk[p][g*9+k];
        float w00 = (1.f-fy)*(1.f-fx)*mw;
        float w01 = (1.f-fy)*fx*mw;
        float w10 = fy*(1.f-fx)*mw;
        float w11 = fy*fx*mw;
        if ((unsigned)y0 < HH && (unsigned)x0 < WW){
            s16x8 v = *(const s16x8*)(vb + ((size_t)(y0*WW+x0))*CM + c0);
            #pragma unroll
            for (int j=0;j<8;j++) acc[j] += w00*b2f(((bf16*)&v)[j]);
        }
        if ((unsigned)y0 < HH && (unsigned)(x0+1) < WW){
            s16x8 v = *(const s16x8*)(vb + ((size_t)(y0*WW+x0+1))*CM + c0);
            #pragma unroll
            for (int j=0;j<8;j++) acc[j] += w01*b2f(((bf16*)&v)[j]);
        }
        if ((unsigned)(y0+1) < HH && (unsigned)x0 < WW){
            s16x8 v = *(const s16x8*)(vb + ((size_t)((y0+1)*WW+x0))*CM + c0);
            #pragma unroll
            for (int j=0;j<8;j++) acc[j] += w10*b2f(((bf16*)&v)[j]);
        }
        if ((unsigned)(y0+1) < HH && (unsigned)(x0+1) < WW){
            s16x8 v = *(const s16x8*)(vb + ((size_t)((y0+1)*WW+x0+1))*CM + c0);
            #pragma unroll
            for (int j=0;j<8;j++) acc[j] += w11*b2f(((bf16*)&v)[j]);
        }
    }
    s16x8 ov;
    #pragma unroll
    for (int j=0;j<8;j++) ((bf16*)&ov)[j] = __float2bfloat16(acc[j]);
    *(s16x8*)(o + (size_t)pix*CM + c0) = ov;
}

// ---------------- K4b: output proj via MFMA (A=Wout^T, B=o^T) + BN2 + SiLU + residual ----------------
__global__ __launch_bounds__(256) void k4b(
    const bf16* __restrict__ o, const bf16* __restrict__ Wf2, const float* __restrict__ scbi,
    const float* __restrict__ xin, float* __restrict__ out)
{
    __shared__ __align__(16) bf16 Bl[64*136];
    int blk = blockIdx.x;
    int n = blk/49; int p0 = (blk%49)*64;
    int tid = threadIdx.x;
    for (int e = tid; e < 1024; e += 256){
        int row = e>>4, seg = e&15;
        *(s16x8*)&Bl[row*136 + seg*8] = *(const s16x8*)(o + ((size_t)n*HWSZ + p0 + row)*CM + seg*8);
    }
    __syncthreads();
    int lane = tid & 63, w = tid >> 6;
    int col = lane & 15, kq = lane >> 4;
    int co0 = w*64;
    s16x8 af[4][4];
    #pragma unroll
    for (int mt=0;mt<4;mt++)
        #pragma unroll
        for (int kc=0;kc<4;kc++)
            af[mt][kc] = *(const s16x8*)(Wf2 + (((size_t)((co0>>4)+mt)*4 + kc)*64 + lane)*8);
    f32x4 acc[4][4];
    #pragma unroll
    for (int mt=0;mt<4;mt++)
        #pragma unroll
        for (int nt=0;nt<4;nt++)
            acc[mt][nt] = (f32x4){0,0,0,0};
    #pragma unroll
    for (int nt=0;nt<4;nt++){
        s16x8 bfr[4];
        #pragma unroll
        for (int kc=0;kc<4;kc++)
            bfr[kc] = *(const s16x8*)&Bl[(nt*16+col)*136 + kc*32 + kq*8];
        #pragma unroll
        for (int mt=0;mt<4;mt++)
            #pragma unroll
            for (int kc=0;kc<4;kc++)
                acc[mt][nt] = __builtin_amdgcn_mfma_f32_16x16x32_bf16(af[mt][kc], bfr[kc], acc[mt][nt], 0, 0, 0);
    }
    #pragma unroll
    for (int mt=0;mt<4;mt++){
        #pragma unroll
        for (int r=0;r<4;r++){
            int co = co0 + mt*16 + kq*4 + r;
            float sc = scbi[co], bi = scbi[256+co];
            #pragma unroll
            for (int nt=0;nt<4;nt++){
                int px = p0 + nt*16 + col;
                size_t idx = ((size_t)(n*C2 + co))*HWSZ + px;
                float z = acc[mt][nt][r]*sc + bi;
                float sl = z/(1.f+expf(-z));
                out[idx] = sl + xin[idx];
            }
        }
    }
}

extern "C" void kernel_launch(void* const* d_in, const int* in_sizes, int n_in,
                              void* d_out, int out_size, void* d_ws, size_t ws_size,
                              hipStream_t stream)
{
    const float* x    = (const float*)d_in[0];
    const float* wcv1 = (const float*)d_in[1];
    const float* bn1g = (const float*)d_in[2];
    const float* bn1b = (const float*)d_in[3];
    const float* bn1m = (const float*)d_in[4];
    const float* bn1v = (const float*)d_in[5];
    const float* wdw  = (const float*)d_in[6];
    const float* bdw  = (const float*)d_in[7];
    const float* lng  = (const float*)d_in[8];
    const float* lnb  = (const float*)d_in[9];
    const float* winp = (const float*)d_in[10];
    const float* binp = (const float*)d_in[11];
    const float* woff = (const float*)d_in[12];
    const float* boff = (const float*)d_in[13];
    const float* wmsk = (const float*)d_in[14];
    const float* bmsk = (const float*)d_in[15];
    const float* wout = (const float*)d_in[16];
    const float* bout = (const float*)d_in[17];
    const float* bn2g = (const float*)d_in[18];
    const float* bn2b = (const float*)d_in[19];
    const float* bn2m = (const float*)d_in[20];
    const float* bn2v = (const float*)d_in[21];

    unsigned char* base = (unsigned char*)d_ws;
    bf16*  Wf   = (bf16*)(base);                    //   589,824
    bf16*  Wf2  = (bf16*)(base + 589824);           //    65,536
    bf16*  Wf3  = (bf16*)(base + 655360);           //    32,768
    bf16*  Wf4  = (bf16*)(base + 688128);           //    28,672
    float* scbi = (float*)(base + 716800);          //     2,048
    float* wdwT = (float*)(base + 718848);          //     4,608
    bf16*  xp   = (bf16*)(base + 723456);           // 13,778,944 (dead after k1; tb/val alias)
    bf16*  tb   = (bf16*)(base + 723456);           //  6,422,528
    bf16*  val  = (bf16*)(base + 7145984);          //  6,422,528
    bf16*  hb   = (bf16*)(base + 14502400);         //  6,422,528
    float* om   = (float*)(base + 20924928);        // 11,239,424
    bf16*  o    = (bf16*)(base + 32164352);         //  6,422,528 (end 38,586,880)

    hipLaunchKernelGGL(k0x, dim3(NN*XP_H*4), dim3(256), 0, stream, x, xp);
    hipLaunchKernelGGL(k0wp, dim3(181), dim3(256), 0, stream,
                       wcv1, wout, winp, woff, wmsk, bn2g, bn2b, bn2m, bn2v, bout, wdw,
                       Wf, Wf2, Wf3, Wf4, scbi, wdwT);
    hipLaunchKernelGGL(k1_mfma, dim3(NN*98), dim3(256), 0, stream,
                       xp, Wf, bn1g, bn1b, bn1m, bn1v, hb);
    hipLaunchKernelGGL(k2v, dim3(LL/8), dim3(128), 0, stream,
                       hb, wdwT, bdw, lng, lnb, tb);
    hipLaunchKernelGGL(k3_gemm, dim3(NN*49), dim3(256), 0, stream,
                       hb, tb, Wf3, Wf4, binp, boff, bmsk, val, om);
    hipLaunchKernelGGL(k4a, dim3(LL/8), dim3(128), 0, stream, val, om, o);
    hipLaunchKernelGGL(k4b, dim3(NN*49), dim3(256), 0, stream, o, Wf2, scbi, x, (float*)d_out);
}

// Round 8
// 243.094 us; speedup vs baseline: 1.2091x; 1.1254x over previous
//
#include <hip/hip_runtime.h>
#include <hip/hip_bf16.h>

typedef __hip_bfloat16 bf16;
typedef float f32x4 __attribute__((ext_vector_type(4)));
typedef short s16x8 __attribute__((ext_vector_type(8)));

#define NN 8
#define HH 56
#define WW 56
#define C1 256
#define CM 128
#define C2 256
#define GG 4
#define K2K 9
#define HWSZ (HH*WW)            // 3136
#define LL (NN*HWSZ)            // 25088
#define EPSF 1e-5f
#define XP_H 58
#define XP_W 58

__device__ __forceinline__ float b2f(bf16 v){ return __bfloat162float(v); }

// ---------------- K0pre: input pad/transpose + all weight repacks in ONE launch ----------------
__global__ __launch_bounds__(256) void k0pre(
    const float* __restrict__ x, const float* __restrict__ w,
    const float* __restrict__ wout, const float* __restrict__ winp,
    const float* __restrict__ woff, const float* __restrict__ wmsk,
    const float* __restrict__ g2, const float* __restrict__ bb2,
    const float* __restrict__ m2, const float* __restrict__ v2,
    const float* __restrict__ bout, const float* __restrict__ wdw,
    bf16* __restrict__ xp, bf16* __restrict__ Wf, bf16* __restrict__ Wf2,
    bf16* __restrict__ Wf3, bf16* __restrict__ Wf4,
    float* __restrict__ scbi, float* __restrict__ wdwT)
{
    int bidg = blockIdx.x;
    if (bidg < 1856){
        // ---- xp: NCHW f32 -> padded NHWC bf16, borders zeroed ----
        __shared__ float lds[64][57];
        int n = bidg / 232; int rem = bidg % 232;
        int yp = rem >> 2; int ci0 = (rem & 3) << 6;
        int tid = threadIdx.x;
        bool interior = (yp >= 1 && yp <= 56);
        if (interior){
            int y = yp - 1;
            for (int e = tid; e < 64*56; e += 256){
                int ci = e / 56, xx = e - (e/56)*56;
                lds[ci][xx] = x[((size_t)((n*C1 + ci0 + ci)*HH) + y)*WW + xx];
            }
            __syncthreads();
        }
        for (int g = tid; g < 464; g += 256){
            int pxp = g >> 3, cig = (g & 7) << 3;
            s16x8 v;
            if (!interior || pxp == 0 || pxp == 57){
                #pragma unroll
                for (int j=0;j<8;j++) ((bf16*)&v)[j] = __float2bfloat16(0.f);
            } else {
                #pragma unroll
                for (int j=0;j<8;j++) ((bf16*)&v)[j] = __float2bfloat16(lds[cig+j][pxp-1]);
            }
            *(s16x8*)(xp + ((size_t)(n*XP_H + yp)*XP_W + pxp)*C1 + ci0 + cig) = v;
        }
        return;
    }
    if (bidg < 2000){
        // ---- Wf: cv1 weights -> B-frag layout ----
        int tlin = (bidg-1856)*256 + threadIdx.x;   // 36864
        int kt  = tlin >> 9;
        int rem = tlin & 511;
        int nt  = rem >> 6;
        int lane = rem & 63;
        int co = nt*16 + (lane & 15);
        int kbase = kt*32 + (lane >> 4)*8;
        bf16* dst = Wf + (size_t)tlin*8;
        #pragma unroll
        for (int j = 0; j < 8; j++){
            int k = kbase + j;
            int tap = k >> 8;
            int ci  = k & 255;
            dst[j] = __float2bfloat16(w[((size_t)co*C1 + ci)*9 + tap]);
        }
        return;
    }
    int t = (bidg-2000)*256 + threadIdx.x;
    if (t < 4096){          // Wf2: A-frag wout^T
        int lane = t & 63; int kc = (t>>6)&3; int mt = t>>8;
        int co = mt*16 + (lane&15); int k0 = kc*32 + (lane>>4)*8;
        bf16* d = Wf2 + (size_t)t*8;
        #pragma unroll
        for (int j=0;j<8;j++) d[j] = __float2bfloat16(wout[(size_t)(k0+j)*C2 + co]);
    } else if (t < 6144){   // Wf3: B-frag winp
        int u = t - 4096; int lane = u&63; int kc=(u>>6)&3; int nt=u>>8;
        int co = nt*16+(lane&15); int k0 = kc*32+(lane>>4)*8;
        bf16* d = Wf3 + (size_t)u*8;
        #pragma unroll
        for (int j=0;j<8;j++) d[j] = __float2bfloat16(winp[(size_t)(k0+j)*CM + co]);
    } else if (t < 7936){   // Wf4: B-frag [woff|wmsk|0]
        int u = t - 6144; int lane=u&63; int kc=(u>>6)&3; int nt=u>>8;
        int nn2 = nt*16+(lane&15); int k0 = kc*32+(lane>>4)*8;
        bf16* d = Wf4 + (size_t)u*8;
        #pragma unroll
        for (int j=0;j<8;j++){
            int k = k0+j; float v = 0.f;
            if (nn2 < 72) v = woff[(size_t)k*72 + nn2];
            else if (nn2 < 108) v = wmsk[(size_t)k*36 + (nn2-72)];
            d[j] = __float2bfloat16(v);
        }
    } else if (t < 8192){
        int co = t - 7936;
        float sc = g2[co]*rsqrtf(v2[co]+EPSF);
        scbi[co] = sc;
        scbi[256+co] = bb2[co] - m2[co]*sc + bout[co]*sc;
    } else if (t < 8192 + 9*CM){
        int u = t - 8192;
        int tap = u >> 7, c = u & 127;
        wdwT[tap*CM + c] = wdw[c*9 + tap];
    }
}

// ---------------- K1: MFMA conv, LDS-staged B, BK=64, flattened M=32 tiles ----------------
__device__ __forceinline__ void stageB(const bf16* __restrict__ Wf, int s, bf16* buf, int w, int lane){
    const bf16* g = Wf + ((size_t)s << 12) + (w << 10) + lane*8;
    bf16* l = buf + (w << 10);
    __builtin_amdgcn_global_load_lds((const __attribute__((address_space(1))) void*)g,
                                     (__attribute__((address_space(3))) void*)l, 16, 0, 0);
    __builtin_amdgcn_global_load_lds((const __attribute__((address_space(1))) void*)(g + 512),
                                     (__attribute__((address_space(3))) void*)(l + 512), 16, 0, 0);
}

__device__ __forceinline__ s16x8 loadA1(const bf16* __restrict__ xp, long abase, int s){
    int tap = s >> 3; int dy = tap/3, dx = tap - dy*3;
    int off = ((dy-1)*XP_W + (dx-1))*C1 + ((s&7)<<5);
    return *(const s16x8*)(xp + abase + off);
}

__global__ __launch_bounds__(256) void k1_mfma(
    const bf16* __restrict__ xp, const bf16* __restrict__ Wf,
    const float* __restrict__ bg, const float* __restrict__ bb,
    const float* __restrict__ bm, const float* __restrict__ bv,
    bf16* __restrict__ hb)
{
    __shared__ __align__(16) bf16 Bbuf[2][8192];   // 2 x 16 KB (BK=64)
    int bid = blockIdx.x;               // 784 = 8*98
    int n = bid/98, p0 = (bid%98)*32;
    int tid = threadIdx.x, lane = tid & 63;
    int w  = tid >> 6;
    int wm = w & 1, wn = w >> 1;
    int kpart = lane >> 4;
    int col = lane & 15;
    int pxA = p0 + wm*16 + col;
    {
        // nothing
    }
    int yA = pxA/WW, xxA = pxA - yA*WW;
    long abase = ((long)((n*XP_H + yA + 1)*XP_W) + (xxA+1))*C1 + kpart*8;

    f32x4 acc[4] = {{0,0,0,0},{0,0,0,0},{0,0,0,0},{0,0,0,0}};

    stageB(Wf, 0, &Bbuf[0][0],    w, lane);
    stageB(Wf, 1, &Bbuf[0][4096], w, lane);
    s16x8 A0 = loadA1(xp, abase, 0);
    s16x8 A1 = loadA1(xp, abase, 1);
    __syncthreads();

    for (int ss = 0; ss < 36; ++ss){
        s16x8 An0 = A0, An1 = A1;
        if (ss + 1 < 36){
            stageB(Wf, 2*ss+2, &Bbuf[(ss+1)&1][0],    w, lane);
            stageB(Wf, 2*ss+3, &Bbuf[(ss+1)&1][4096], w, lane);
            An0 = loadA1(xp, abase, 2*ss+2);
            An1 = loadA1(xp, abase, 2*ss+3);
        }
        const bf16* bufp = &Bbuf[ss&1][0] + (wn << 11) + lane*8;
        #pragma unroll
        for (int ct = 0; ct < 4; ++ct){
            s16x8 bfrag = *(const s16x8*)(bufp + (ct << 9));
            acc[ct] = __builtin_amdgcn_mfma_f32_16x16x32_bf16(A0, bfrag, acc[ct], 0, 0, 0);
        }
        #pragma unroll
        for (int ct = 0; ct < 4; ++ct){
            s16x8 bfrag = *(const s16x8*)(bufp + 4096 + (ct << 9));
            acc[ct] = __builtin_amdgcn_mfma_f32_16x16x32_bf16(A1, bfrag, acc[ct], 0, 0, 0);
        }
        __syncthreads();
        A0 = An0; A1 = An1;
    }

    // epilogue: C layout col -> co, kpart*4+r -> px
    int pxO = p0 + wm*16 + kpart*4;
    #pragma unroll
    for (int ct = 0; ct < 4; ++ct){
        int co = (wn << 6) + (ct << 4) + col;
        float sc = bg[co] * rsqrtf(bv[co] + EPSF);
        float bi = bb[co] - bm[co]*sc;
        #pragma unroll
        for (int r = 0; r < 4; ++r){
            int px = pxO + r;
            float z = acc[ct][r]*sc + bi;
            float sl = z / (1.f + expf(-z));
            hb[((size_t)n*HWSZ + px)*CM + co] = __float2bfloat16(sl);
        }
    }
}

// ---------------- K3f: dw3x3+LN+GELU (fused) + MFMA GEMMs val/om ----------------
__global__ __launch_bounds__(256) void k3f(
    const bf16* __restrict__ hb,
    const float* __restrict__ wdwT, const float* __restrict__ bdw,
    const float* __restrict__ lng, const float* __restrict__ lnb,
    const bf16* __restrict__ Wf3, const bf16* __restrict__ Wf4,
    const float* __restrict__ binp, const float* __restrict__ boff, const float* __restrict__ bmsk,
    bf16* __restrict__ val, float* __restrict__ om)
{
    __shared__ __align__(16) bf16 Ah[64*136];
    __shared__ __align__(16) bf16 At[64*136];
    int blk = blockIdx.x;               // 392
    int n = blk/49; int p0 = (blk%49)*64;
    size_t pixbase = (size_t)n*HWSZ + p0;
    int tid = threadIdx.x;
    for (int e = tid; e < 1024; e += 256){
        int row = e>>4, seg = e&15;
        *(s16x8*)&Ah[row*136 + seg*8] = *(const s16x8*)(hb + (pixbase+row)*CM + seg*8);
    }
    {
        int slot = tid & 15, c0 = slot*8;
        int pbase = (tid >> 4) * 4;
        const bf16* hbase = hb + (size_t)n*HWSZ*CM;
        float4 b0 = *(const float4*)(bdw + c0);
        float4 b1 = *(const float4*)(bdw + c0 + 4);
        float4 g0 = *(const float4*)(lng + c0); float4 g1 = *(const float4*)(lng + c0+4);
        float4 q0 = *(const float4*)(lnb + c0); float4 q1 = *(const float4*)(lnb + c0+4);
        float gv[8]={g0.x,g0.y,g0.z,g0.w,g1.x,g1.y,g1.z,g1.w};
        float qv[8]={q0.x,q0.y,q0.z,q0.w,q1.x,q1.y,q1.z,q1.w};
        #pragma unroll
        for (int i=0;i<4;i++){
            int pxl = p0 + pbase + i;
            int y = pxl/WW, xq = pxl - (pxl/WW)*WW;
            float acc[8] = {b0.x,b0.y,b0.z,b0.w,b1.x,b1.y,b1.z,b1.w};
            #pragma unroll
            for (int tap=0; tap<9; tap++){
                int dy=tap/3, dx=tap%3;
                int yy=y+dy-1, xx=xq+dx-1;
                if ((unsigned)yy < HH && (unsigned)xx < WW){
                    s16x8 v = *(const s16x8*)(hbase + ((size_t)(yy*WW+xx))*CM + c0);
                    float4 w0 = *(const float4*)(wdwT + tap*CM + c0);
                    float4 w1 = *(const float4*)(wdwT + tap*CM + c0 + 4);
                    float wv[8] = {w0.x,w0.y,w0.z,w0.w,w1.x,w1.y,w1.z,w1.w};
                    #pragma unroll
                    for (int j=0;j<8;j++) acc[j] += b2f(((bf16*)&v)[j]) * wv[j];
                }
            }
            float s1=0.f, s2=0.f;
            #pragma unroll
            for (int j=0;j<8;j++){ s1 += acc[j]; s2 += acc[j]*acc[j]; }
            #pragma unroll
            for (int off=1; off<16; off<<=1){
                s1 += __shfl_xor(s1, off);
                s2 += __shfl_xor(s2, off);
            }
            float mean = s1*(1.f/CM);
            float var  = fmaxf(s2*(1.f/CM) - mean*mean, 0.f);
            float inv  = rsqrtf(var + EPSF);
            s16x8 ov;
            #pragma unroll
            for (int j=0;j<8;j++){
                float z = (acc[j]-mean)*inv*gv[j] + qv[j];
                float gl = 0.5f*z*(1.f + erff(z*0.70710678118654752f));
                ((bf16*)&ov)[j] = __float2bfloat16(gl);
            }
            *(s16x8*)&At[(pbase+i)*136 + c0] = ov;
        }
    }
    __syncthreads();
    int lane = tid & 63, w = tid >> 6;
    int col = lane & 15, kq = lane >> 4;
    s16x8 a0[4], a1[4];
    #pragma unroll
    for (int kc=0;kc<4;kc++){
        a0[kc] = *(const s16x8*)&Ah[(w*16+col)*136 + kc*32 + kq*8];
        a1[kc] = *(const s16x8*)&At[(w*16+col)*136 + kc*32 + kq*8];
    }
    int pxo = p0 + w*16 + kq*4;
    #pragma unroll
    for (int nt=0; nt<8; nt++){
        f32x4 acc = {0,0,0,0};
        #pragma unroll
        for (int kc=0;kc<4;kc++){
            s16x8 b = *(const s16x8*)(Wf3 + ((size_t)(nt*4+kc)*64 + lane)*8);
            acc = __builtin_amdgcn_mfma_f32_16x16x32_bf16(a0[kc], b, acc, 0, 0, 0);
        }
        int co = nt*16 + col;
        float bia = binp[co];
        #pragma unroll
        for (int r=0;r<4;r++)
            val[((size_t)n*HWSZ + pxo + r)*CM + co] = __float2bfloat16(acc[r] + bia);
    }
    #pragma unroll
    for (int nt=0; nt<7; nt++){
        f32x4 acc = {0,0,0,0};
        #pragma unroll
        for (int kc=0;kc<4;kc++){
            s16x8 b = *(const s16x8*)(Wf4 + ((size_t)(nt*4+kc)*64 + lane)*8);
            acc = __builtin_amdgcn_mfma_f32_16x16x32_bf16(a1[kc], b, acc, 0, 0, 0);
        }
        int nn2 = nt*16 + col;
        float bia = (nn2<72) ? boff[nn2] : (nn2<108 ? bmsk[nn2-72] : 0.f);
        #pragma unroll
        for (int r=0;r<4;r++)
            om[((size_t)n*HWSZ + pxo + r)*112 + nn2] = acc[r] + bia;
    }
}

// ---------------- K4a: softmax + DCNv3 bilinear gather, 8 pixels/block, 16B loads ----------------
__global__ __launch_bounds__(128) void k4a(
    const bf16* __restrict__ valb, const float* __restrict__ om, bf16* __restrict__ o)
{
    __shared__ float omb[8][112];
    __shared__ float mk[8][36];
    int t = threadIdx.x;
    int pix0 = blockIdx.x*8;
    for (int e = t; e < 8*112; e += 128){
        int p = e / 112, q = e - (e/112)*112;
        omb[p][q] = om[(size_t)(pix0+p)*112 + q];
    }
    __syncthreads();
    if (t < 32){
        int p = t >> 2, g = t & 3;
        float mx = omb[p][72+g*9];
        #pragma unroll
        for (int j=1;j<9;j++) mx = fmaxf(mx, omb[p][72+g*9+j]);
        float sum=0.f; float e9[9];
        #pragma unroll
        for (int j=0;j<9;j++){ e9[j] = expf(omb[p][72+g*9+j]-mx); sum += e9[j]; }
        float inv = 1.f/sum;
        #pragma unroll
        for (int j=0;j<9;j++) mk[p][g*9+j] = e9[j]*inv;
    }
    __syncthreads();
    int p = t >> 4, s = t & 15;
    int g = s >> 2;
    int c0 = s*8;
    int pix = pix0 + p;
    int n = pix / HWSZ, rem = pix % HWSZ;
    int y = rem / WW, xq = rem % WW;
    const bf16* vb = valb + (size_t)n*HWSZ*CM;
    float acc[8] = {0,0,0,0,0,0,0,0};
    #pragma unroll
    for (int k=0;k<9;k++){
        float oxv = omb[p][g*18 + k*2];
        float oyv = omb[p][g*18 + k*2 + 1];
        float sx = (float)xq + (float)(k/3) - 1.f + oxv;
        float sy = (float)y  + (float)(k%3) - 1.f + oyv;
        float x0f = floorf(sx), y0f = floorf(sy);
        float fx = sx - x0f, fy = sy - y0f;
        int x0 = (int)x0f, y0 = (int)y0f;
        float mw = mk[p][g*9+k];
        float w00 = (1.f-fy)*(1.f-fx)*mw;
        float w01 = (1.f-fy)*fx*mw;
        float w10 = fy*(1.f-fx)*mw;
        float w11 = fy*fx*mw;
        if ((unsigned)y0 < HH && (unsigned)x0 < WW){
            s16x8 v = *(const s16x8*)(vb + ((size_t)(y0*WW+x0))*CM + c0);
            #pragma unroll
            for (int j=0;j<8;j++) acc[j] += w00*b2f(((bf16*)&v)[j]);
        }
        if ((unsigned)y0 < HH && (unsigned)(x0+1) < WW){
            s16x8 v = *(const s16x8*)(vb + ((size_t)(y0*WW+x0+1))*CM + c0);
            #pragma unroll
            for (int j=0;j<8;j++) acc[j] += w01*b2f(((bf16*)&v)[j]);
        }
        if ((unsigned)(y0+1) < HH && (unsigned)x0 < WW){
            s16x8 v = *(const s16x8*)(vb + ((size_t)((y0+1)*WW+x0))*CM + c0);
            #pragma unroll
            for (int j=0;j<8;j++) acc[j] += w10*b2f(((bf16*)&v)[j]);
        }
        if ((unsigned)(y0+1) < HH && (unsigned)(x0+1) < WW){
            s16x8 v = *(const s16x8*)(vb + ((size_t)((y0+1)*WW+x0+1))*CM + c0);
            #pragma unroll
            for (int j=0;j<8;j++) acc[j] += w11*b2f(((bf16*)&v)[j]);
        }
    }
    s16x8 ov;
    #pragma unroll
    for (int j=0;j<8;j++) ((bf16*)&ov)[j] = __float2bfloat16(acc[j]);
    *(s16x8*)(o + (size_t)pix*CM + c0) = ov;
}

// ---------------- K4b: output proj via MFMA (A=Wout^T, B=o^T) + BN2 + SiLU + residual ----------------
__global__ __launch_bounds__(256) void k4b(
    const bf16* __restrict__ o, const bf16* __restrict__ Wf2, const float* __restrict__ scbi,
    const float* __restrict__ xin, float* __restrict__ out)
{
    __shared__ __align__(16) bf16 Bl[64*136];
    int blk = blockIdx.x;
    int n = blk/49; int p0 = (blk%49)*64;
    int tid = threadIdx.x;
    for (int e = tid; e < 1024; e += 256){
        int row = e>>4, seg = e&15;
        *(s16x8*)&Bl[row*136 + seg*8] = *(const s16x8*)(o + ((size_t)n*HWSZ + p0 + row)*CM + seg*8);
    }
    __syncthreads();
    int lane = tid & 63, w = tid >> 6;
    int col = lane & 15, kq = lane >> 4;
    int co0 = w*64;
    s16x8 af[4][4];
    #pragma unroll
    for (int mt=0;mt<4;mt++)
        #pragma unroll
        for (int kc=0;kc<4;kc++)
            af[mt][kc] = *(const s16x8*)(Wf2 + (((size_t)((co0>>4)+mt)*4 + kc)*64 + lane)*8);
    f32x4 acc[4][4];
    #pragma unroll
    for (int mt=0;mt<4;mt++)
        #pragma unroll
        for (int nt=0;nt<4;nt++)
            acc[mt][nt] = (f32x4){0,0,0,0};
    #pragma unroll
    for (int nt=0;nt<4;nt++){
        s16x8 bfr[4];
        #pragma unroll
        for (int kc=0;kc<4;kc++)
            bfr[kc] = *(const s16x8*)&Bl[(nt*16+col)*136 + kc*32 + kq*8];
        #pragma unroll
        for (int mt=0;mt<4;mt++)
            #pragma unroll
            for (int kc=0;kc<4;kc++)
                acc[mt][nt] = __builtin_amdgcn_mfma_f32_16x16x32_bf16(af[mt][kc], bfr[kc], acc[mt][nt], 0, 0, 0);
    }
    #pragma unroll
    for (int mt=0;mt<4;mt++){
        #pragma unroll
        for (int r=0;r<4;r++){
            int co = co0 + mt*16 + kq*4 + r;
            float sc = scbi[co], bi = scbi[256+co];
            #pragma unroll
            for (int nt=0;nt<4;nt++){
                int px = p0 + nt*16 + col;
                size_t idx = ((size_t)(n*C2 + co))*HWSZ + px;
                float z = acc[mt][nt][r]*sc + bi;
                float sl = z/(1.f+expf(-z));
                out[idx] = sl + xin[idx];
            }
        }
    }
}

extern "C" void kernel_launch(void* const* d_in, const int* in_sizes, int n_in,
                              void* d_out, int out_size, void* d_ws, size_t ws_size,
                              hipStream_t stream)
{
    const float* x    = (const float*)d_in[0];
    const float* wcv1 = (const float*)d_in[1];
    const float* bn1g = (const float*)d_in[2];
    const float* bn1b = (const float*)d_in[3];
    const float* bn1m = (const float*)d_in[4];
    const float* bn1v = (const float*)d_in[5];
    const float* wdw  = (const float*)d_in[6];
    const float* bdw  = (const float*)d_in[7];
    const float* lng  = (const float*)d_in[8];
    const float* lnb  = (const float*)d_in[9];
    const float* winp = (const float*)d_in[10];
    const float* binp = (const float*)d_in[11];
    const float* woff = (const float*)d_in[12];
    const float* boff = (const float*)d_in[13];
    const float* wmsk = (const float*)d_in[14];
    const float* bmsk = (const float*)d_in[15];
    const float* wout = (const float*)d_in[16];
    const float* bout = (const float*)d_in[17];
    const float* bn2g = (const float*)d_in[18];
    const float* bn2b = (const float*)d_in[19];
    const float* bn2m = (const float*)d_in[20];
    const float* bn2v = (const float*)d_in[21];

    unsigned char* base = (unsigned char*)d_ws;
    bf16*  Wf   = (bf16*)(base);                    //   589,824
    bf16*  Wf2  = (bf16*)(base + 589824);           //    65,536
    bf16*  Wf3  = (bf16*)(base + 655360);           //    32,768
    bf16*  Wf4  = (bf16*)(base + 688128);           //    28,672
    float* scbi = (float*)(base + 716800);          //     2,048
    float* wdwT = (float*)(base + 718848);          //     4,608
    bf16*  xp   = (bf16*)(base + 723456);           // 13,778,944 (dead after k1; val aliases)
    bf16*  val  = (bf16*)(base + 723456);           //  6,422,528
    bf16*  hb   = (bf16*)(base + 14502400);         //  6,422,528
    float* om   = (float*)(base + 20924928);        // 11,239,424
    bf16*  o    = (bf16*)(base + 32164352);         //  6,422,528 (end 38,586,880)

    hipLaunchKernelGGL(k0pre, dim3(2037), dim3(256), 0, stream,
                       x, wcv1, wout, winp, woff, wmsk, bn2g, bn2b, bn2m, bn2v, bout, wdw,
                       xp, Wf, Wf2, Wf3, Wf4, scbi, wdwT);
    hipLaunchKernelGGL(k1_mfma, dim3(NN*98), dim3(256), 0, stream,
                       xp, Wf, bn1g, bn1b, bn1m, bn1v, hb);
    hipLaunchKernelGGL(k3f, dim3(NN*49), dim3(256), 0, stream,
                       hb, wdwT, bdw, lng, lnb, Wf3, Wf4, binp, boff, bmsk, val, om);
    hipLaunchKernelGGL(k4a, dim3(LL/8), dim3(128), 0, stream, val, om, o);
    hipLaunchKernelGGL(k4b, dim3(NN*49), dim3(256), 0, stream, o, Wf2, scbi, x, (float*)d_out);
}

// Round 9
// 231.288 us; speedup vs baseline: 1.2708x; 1.0510x over previous
//
#include <hip/hip_runtime.h>
#include <hip/hip_bf16.h>

typedef __hip_bfloat16 bf16;
typedef float f32x4 __attribute__((ext_vector_type(4)));
typedef short s16x8 __attribute__((ext_vector_type(8)));

#define NN 8
#define HH 56
#define WW 56
#define C1 256
#define CM 128
#define C2 256
#define GG 4
#define K2K 9
#define HWSZ (HH*WW)            // 3136
#define LL (NN*HWSZ)            // 25088
#define EPSF 1e-5f
#define XP_H 58
#define XP_W 58

__device__ __forceinline__ float b2f(bf16 v){ return __bfloat162float(v); }

// ---------------- K0pre: input pad/transpose + all weight repacks in ONE launch ----------------
__global__ __launch_bounds__(256) void k0pre(
    const float* __restrict__ x, const float* __restrict__ w,
    const float* __restrict__ wout, const float* __restrict__ winp,
    const float* __restrict__ woff, const float* __restrict__ wmsk,
    const float* __restrict__ g2, const float* __restrict__ bb2,
    const float* __restrict__ m2, const float* __restrict__ v2,
    const float* __restrict__ bout, const float* __restrict__ wdw,
    bf16* __restrict__ xp, bf16* __restrict__ Wf, bf16* __restrict__ Wf2,
    bf16* __restrict__ Wf3, bf16* __restrict__ Wf4,
    float* __restrict__ scbi, float* __restrict__ wdwT)
{
    int bidg = blockIdx.x;
    if (bidg < 1856){
        __shared__ float lds[64][57];
        int n = bidg / 232; int rem = bidg % 232;
        int yp = rem >> 2; int ci0 = (rem & 3) << 6;
        int tid = threadIdx.x;
        bool interior = (yp >= 1 && yp <= 56);
        if (interior){
            int y = yp - 1;
            for (int e = tid; e < 64*56; e += 256){
                int ci = e / 56, xx = e - (e/56)*56;
                lds[ci][xx] = x[((size_t)((n*C1 + ci0 + ci)*HH) + y)*WW + xx];
            }
            __syncthreads();
        }
        for (int g = tid; g < 464; g += 256){
            int pxp = g >> 3, cig = (g & 7) << 3;
            s16x8 v;
            if (!interior || pxp == 0 || pxp == 57){
                #pragma unroll
                for (int j=0;j<8;j++) ((bf16*)&v)[j] = __float2bfloat16(0.f);
            } else {
                #pragma unroll
                for (int j=0;j<8;j++) ((bf16*)&v)[j] = __float2bfloat16(lds[cig+j][pxp-1]);
            }
            *(s16x8*)(xp + ((size_t)(n*XP_H + yp)*XP_W + pxp)*C1 + ci0 + cig) = v;
        }
        return;
    }
    if (bidg < 2000){
        int tlin = (bidg-1856)*256 + threadIdx.x;   // 36864
        int kt  = tlin >> 9;
        int rem = tlin & 511;
        int nt  = rem >> 6;
        int lane = rem & 63;
        int co = nt*16 + (lane & 15);
        int kbase = kt*32 + (lane >> 4)*8;
        bf16* dst = Wf + (size_t)tlin*8;
        #pragma unroll
        for (int j = 0; j < 8; j++){
            int k = kbase + j;
            int tap = k >> 8;
            int ci  = k & 255;
            dst[j] = __float2bfloat16(w[((size_t)co*C1 + ci)*9 + tap]);
        }
        return;
    }
    int t = (bidg-2000)*256 + threadIdx.x;
    if (t < 4096){          // Wf2: A-frag wout^T
        int lane = t & 63; int kc = (t>>6)&3; int mt = t>>8;
        int co = mt*16 + (lane&15); int k0 = kc*32 + (lane>>4)*8;
        bf16* d = Wf2 + (size_t)t*8;
        #pragma unroll
        for (int j=0;j<8;j++) d[j] = __float2bfloat16(wout[(size_t)(k0+j)*C2 + co]);
    } else if (t < 6144){   // Wf3: B-frag winp
        int u = t - 4096; int lane = u&63; int kc=(u>>6)&3; int nt=u>>8;
        int co = nt*16+(lane&15); int k0 = kc*32+(lane>>4)*8;
        bf16* d = Wf3 + (size_t)u*8;
        #pragma unroll
        for (int j=0;j<8;j++) d[j] = __float2bfloat16(winp[(size_t)(k0+j)*CM + co]);
    } else if (t < 7936){   // Wf4: B-frag [woff|wmsk|0]
        int u = t - 6144; int lane=u&63; int kc=(u>>6)&3; int nt=u>>8;
        int nn2 = nt*16+(lane&15); int k0 = kc*32+(lane>>4)*8;
        bf16* d = Wf4 + (size_t)u*8;
        #pragma unroll
        for (int j=0;j<8;j++){
            int k = k0+j; float v = 0.f;
            if (nn2 < 72) v = woff[(size_t)k*72 + nn2];
            else if (nn2 < 108) v = wmsk[(size_t)k*36 + (nn2-72)];
            d[j] = __float2bfloat16(v);
        }
    } else if (t < 8192){
        int co = t - 7936;
        float sc = g2[co]*rsqrtf(v2[co]+EPSF);
        scbi[co] = sc;
        scbi[256+co] = bb2[co] - m2[co]*sc + bout[co]*sc;
    } else if (t < 8192 + 9*CM){
        int u = t - 8192;
        int tap = u >> 7, c = u & 127;
        wdwT[tap*CM + c] = wdw[c*9 + tap];
    }
}

// ---------------- K1: MFMA conv, LDS-staged B, BK=64, flattened M=32 tiles ----------------
__device__ __forceinline__ void stageB(const bf16* __restrict__ Wf, int s, bf16* buf, int w, int lane){
    const bf16* g = Wf + ((size_t)s << 12) + (w << 10) + lane*8;
    bf16* l = buf + (w << 10);
    __builtin_amdgcn_global_load_lds((const __attribute__((address_space(1))) void*)g,
                                     (__attribute__((address_space(3))) void*)l, 16, 0, 0);
    __builtin_amdgcn_global_load_lds((const __attribute__((address_space(1))) void*)(g + 512),
                                     (__attribute__((address_space(3))) void*)(l + 512), 16, 0, 0);
}

__device__ __forceinline__ s16x8 loadA1(const bf16* __restrict__ xp, long abase, int s){
    int tap = s >> 3; int dy = tap/3, dx = tap - dy*3;
    int off = ((dy-1)*XP_W + (dx-1))*C1 + ((s&7)<<5);
    return *(const s16x8*)(xp + abase + off);
}

__global__ __launch_bounds__(256) void k1_mfma(
    const bf16* __restrict__ xp, const bf16* __restrict__ Wf,
    const float* __restrict__ bg, const float* __restrict__ bb,
    const float* __restrict__ bm, const float* __restrict__ bv,
    bf16* __restrict__ hb)
{
    __shared__ __align__(16) bf16 Bbuf[2][8192];   // 2 x 16 KB (BK=64)
    int bid = blockIdx.x;               // 784 = 8*98
    int n = bid/98, p0 = (bid%98)*32;
    int tid = threadIdx.x, lane = tid & 63;
    int w  = tid >> 6;
    int wm = w & 1, wn = w >> 1;
    int kpart = lane >> 4;
    int col = lane & 15;
    int pxA = p0 + wm*16 + col;
    int yA = pxA/WW, xxA = pxA - yA*WW;
    long abase = ((long)((n*XP_H + yA + 1)*XP_W) + (xxA+1))*C1 + kpart*8;

    f32x4 acc[4] = {{0,0,0,0},{0,0,0,0},{0,0,0,0},{0,0,0,0}};

    stageB(Wf, 0, &Bbuf[0][0],    w, lane);
    stageB(Wf, 1, &Bbuf[0][4096], w, lane);
    s16x8 A0 = loadA1(xp, abase, 0);
    s16x8 A1 = loadA1(xp, abase, 1);
    __syncthreads();

    for (int ss = 0; ss < 36; ++ss){
        s16x8 An0 = A0, An1 = A1;
        if (ss + 1 < 36){
            stageB(Wf, 2*ss+2, &Bbuf[(ss+1)&1][0],    w, lane);
            stageB(Wf, 2*ss+3, &Bbuf[(ss+1)&1][4096], w, lane);
            An0 = loadA1(xp, abase, 2*ss+2);
            An1 = loadA1(xp, abase, 2*ss+3);
        }
        const bf16* bufp = &Bbuf[ss&1][0] + (wn << 11) + lane*8;
        #pragma unroll
        for (int ct = 0; ct < 4; ++ct){
            s16x8 bfrag = *(const s16x8*)(bufp + (ct << 9));
            acc[ct] = __builtin_amdgcn_mfma_f32_16x16x32_bf16(A0, bfrag, acc[ct], 0, 0, 0);
        }
        #pragma unroll
        for (int ct = 0; ct < 4; ++ct){
            s16x8 bfrag = *(const s16x8*)(bufp + 4096 + (ct << 9));
            acc[ct] = __builtin_amdgcn_mfma_f32_16x16x32_bf16(A1, bfrag, acc[ct], 0, 0, 0);
        }
        __syncthreads();
        A0 = An0; A1 = An1;
    }

    int pxO = p0 + wm*16 + kpart*4;
    #pragma unroll
    for (int ct = 0; ct < 4; ++ct){
        int co = (wn << 6) + (ct << 4) + col;
        float sc = bg[co] * rsqrtf(bv[co] + EPSF);
        float bi = bb[co] - bm[co]*sc;
        #pragma unroll
        for (int r = 0; r < 4; ++r){
            int px = pxO + r;
            float z = acc[ct][r]*sc + bi;
            float sl = z / (1.f + expf(-z));
            hb[((size_t)n*HWSZ + px)*CM + co] = __float2bfloat16(sl);
        }
    }
}

// ---------------- K2: depthwise 3x3 + LN + GELU, 8 pixels/block (high TLP) ----------------
__global__ __launch_bounds__(128) void k2v(
    const bf16* __restrict__ hb, const float* __restrict__ wdwT, const float* __restrict__ bdw,
    const float* __restrict__ lng, const float* __restrict__ lnb, bf16* __restrict__ tb)
{
    int t = threadIdx.x;
    int p = t >> 4, s = t & 15;
    int pix = blockIdx.x*8 + p;
    int n = pix / HWSZ, rem = pix % HWSZ;
    int y = rem / WW, xq = rem % WW;
    int c0 = s*8;
    const bf16* hbase = hb + (size_t)n*HWSZ*CM;
    float acc[8];
    {
        float4 b0 = *(const float4*)(bdw + c0);
        float4 b1 = *(const float4*)(bdw + c0 + 4);
        acc[0]=b0.x; acc[1]=b0.y; acc[2]=b0.z; acc[3]=b0.w;
        acc[4]=b1.x; acc[5]=b1.y; acc[6]=b1.z; acc[7]=b1.w;
    }
    #pragma unroll
    for (int tap=0; tap<9; tap++){
        int dy=tap/3, dx=tap%3;
        int yy=y+dy-1, xx=xq+dx-1;
        if ((unsigned)yy < HH && (unsigned)xx < WW){
            s16x8 v = *(const s16x8*)(hbase + ((size_t)(yy*WW+xx))*CM + c0);
            float4 w0 = *(const float4*)(wdwT + tap*CM + c0);
            float4 w1 = *(const float4*)(wdwT + tap*CM + c0 + 4);
            float wv[8] = {w0.x,w0.y,w0.z,w0.w,w1.x,w1.y,w1.z,w1.w};
            #pragma unroll
            for (int j=0;j<8;j++)
                acc[j] += b2f(((bf16*)&v)[j]) * wv[j];
        }
    }
    float s1=0.f, s2=0.f;
    #pragma unroll
    for (int j=0;j<8;j++){ s1 += acc[j]; s2 += acc[j]*acc[j]; }
    #pragma unroll
    for (int off=1; off<16; off<<=1){
        s1 += __shfl_xor(s1, off);
        s2 += __shfl_xor(s2, off);
    }
    float mean = s1*(1.f/CM);
    float var  = fmaxf(s2*(1.f/CM) - mean*mean, 0.f);
    float inv  = rsqrtf(var + EPSF);
    float4 g0 = *(const float4*)(lng + c0); float4 g1 = *(const float4*)(lng + c0+4);
    float4 q0 = *(const float4*)(lnb + c0); float4 q1 = *(const float4*)(lnb + c0+4);
    float gv[8]={g0.x,g0.y,g0.z,g0.w,g1.x,g1.y,g1.z,g1.w};
    float qv[8]={q0.x,q0.y,q0.z,q0.w,q1.x,q1.y,q1.z,q1.w};
    s16x8 ov;
    #pragma unroll
    for (int j=0;j<8;j++){
        float z = (acc[j]-mean)*inv*gv[j] + qv[j];
        float gl = 0.5f*z*(1.f + erff(z*0.70710678118654752f));
        ((bf16*)&ov)[j] = __float2bfloat16(gl);
    }
    *(s16x8*)(tb + (size_t)pix*CM + c0) = ov;
}

// ---------------- K3: MFMA GEMMs, M=32 tiles (784 blocks for TLP) ----------------
__global__ __launch_bounds__(256) void k3_gemm(
    const bf16* __restrict__ hb, const bf16* __restrict__ tb,
    const bf16* __restrict__ Wf3, const bf16* __restrict__ Wf4,
    const float* __restrict__ binp, const float* __restrict__ boff, const float* __restrict__ bmsk,
    bf16* __restrict__ val, float* __restrict__ om)
{
    __shared__ __align__(16) bf16 Ah[32*136];
    __shared__ __align__(16) bf16 At[32*136];
    int blk = blockIdx.x;               // 784 = 8*98
    int n = blk/98; int p0 = (blk%98)*32;
    size_t pixbase = (size_t)n*HWSZ + p0;
    int tid = threadIdx.x;
    for (int e = tid; e < 512; e += 256){
        int row = e>>4, seg = e&15;
        *(s16x8*)&Ah[row*136 + seg*8] = *(const s16x8*)(hb + (pixbase+row)*CM + seg*8);
        *(s16x8*)&At[row*136 + seg*8] = *(const s16x8*)(tb + (pixbase+row)*CM + seg*8);
    }
    __syncthreads();
    int lane = tid & 63, w = tid >> 6;
    int col = lane & 15, kq = lane >> 4;
    int mt = w & 1, wn = w >> 1;       // mt: M-tile, wn: N-half
    s16x8 a0[4], a1[4];
    #pragma unroll
    for (int kc=0;kc<4;kc++){
        a0[kc] = *(const s16x8*)&Ah[(mt*16+col)*136 + kc*32 + kq*8];
        a1[kc] = *(const s16x8*)&At[(mt*16+col)*136 + kc*32 + kq*8];
    }
    int pxo = p0 + mt*16 + kq*4;
    // GEMM1: val (N=128 -> 8 nt tiles, 4 per N-half)
    #pragma unroll
    for (int nti=0; nti<4; nti++){
        int nt = wn*4 + nti;
        f32x4 acc = {0,0,0,0};
        #pragma unroll
        for (int kc=0;kc<4;kc++){
            s16x8 b = *(const s16x8*)(Wf3 + ((size_t)(nt*4+kc)*64 + lane)*8);
            acc = __builtin_amdgcn_mfma_f32_16x16x32_bf16(a0[kc], b, acc, 0, 0, 0);
        }
        int co = nt*16 + col;
        float bia = binp[co];
        #pragma unroll
        for (int r=0;r<4;r++)
            val[((size_t)n*HWSZ + pxo + r)*CM + co] = __float2bfloat16(acc[r] + bia);
    }
    // GEMM2: om (N=112 -> 7 nt tiles: wn=0 -> 0..3, wn=1 -> 4..6)
    #pragma unroll
    for (int nti=0; nti<4; nti++){
        int nt = wn*4 + nti;
        if (nt < 7){
            f32x4 acc = {0,0,0,0};
            #pragma unroll
            for (int kc=0;kc<4;kc++){
                s16x8 b = *(const s16x8*)(Wf4 + ((size_t)(nt*4+kc)*64 + lane)*8);
                acc = __builtin_amdgcn_mfma_f32_16x16x32_bf16(a1[kc], b, acc, 0, 0, 0);
            }
            int nn2 = nt*16 + col;
            float bia = (nn2<72) ? boff[nn2] : (nn2<108 ? bmsk[nn2-72] : 0.f);
            #pragma unroll
            for (int r=0;r<4;r++)
                om[((size_t)n*HWSZ + pxo + r)*112 + nn2] = acc[r] + bia;
        }
    }
}

// ---------------- K4a: softmax + DCNv3 bilinear gather, 8 pixels/block, 16B loads ----------------
__global__ __launch_bounds__(128) void k4a(
    const bf16* __restrict__ valb, const float* __restrict__ om, bf16* __restrict__ o)
{
    __shared__ float omb[8][112];
    __shared__ float mk[8][36];
    int t = threadIdx.x;
    int pix0 = blockIdx.x*8;
    for (int e = t; e < 8*112; e += 128){
        int p = e / 112, q = e - (e/112)*112;
        omb[p][q] = om[(size_t)(pix0+p)*112 + q];
    }
    __syncthreads();
    if (t < 32){
        int p = t >> 2, g = t & 3;
        float mx = omb[p][72+g*9];
        #pragma unroll
        for (int j=1;j<9;j++) mx = fmaxf(mx, omb[p][72+g*9+j]);
        float sum=0.f; float e9[9];
        #pragma unroll
        for (int j=0;j<9;j++){ e9[j] = expf(omb[p][72+g*9+j]-mx); sum += e9[j]; }
        float inv = 1.f/sum;
        #pragma unroll
        for (int j=0;j<9;j++) mk[p][g*9+j] = e9[j]*inv;
    }
    __syncthreads();
    int p = t >> 4, s = t & 15;
    int g = s >> 2;
    int c0 = s*8;
    int pix = pix0 + p;
    int n = pix / HWSZ, rem = pix % HWSZ;
    int y = rem / WW, xq = rem % WW;
    const bf16* vb = valb + (size_t)n*HWSZ*CM;
    float acc[8] = {0,0,0,0,0,0,0,0};
    #pragma unroll
    for (int k=0;k<9;k++){
        float oxv = omb[p][g*18 + k*2];
        float oyv = omb[p][g*18 + k*2 + 1];
        float sx = (float)xq + (float)(k/3) - 1.f + oxv;
        float sy = (float)y  + (float)(k%3) - 1.f + oyv;
        float x0f = floorf(sx), y0f = floorf(sy);
        float fx = sx - x0f, fy = sy - y0f;
        int x0 = (int)x0f, y0 = (int)y0f;
        float mw = mk[p][g*9+k];
        float w00 = (1.f-fy)*(1.f-fx)*mw;
        float w01 = (1.f-fy)*fx*mw;
        float w10 = fy*(1.f-fx)*mw;
        float w11 = fy*fx*mw;
        if ((unsigned)y0 < HH && (unsigned)x0 < WW){
            s16x8 v = *(const s16x8*)(vb + ((size_t)(y0*WW+x0))*CM + c0);
            #pragma unroll
            for (int j=0;j<8;j++) acc[j] += w00*b2f(((bf16*)&v)[j]);
        }
        if ((unsigned)y0 < HH && (unsigned)(x0+1) < WW){
            s16x8 v = *(const s16x8*)(vb + ((size_t)(y0*WW+x0+1))*CM + c0);
            #pragma unroll
            for (int j=0;j<8;j++) acc[j] += w01*b2f(((bf16*)&v)[j]);
        }
        if ((unsigned)(y0+1) < HH && (unsigned)x0 < WW){
            s16x8 v = *(const s16x8*)(vb + ((size_t)((y0+1)*WW+x0))*CM + c0);
            #pragma unroll
            for (int j=0;j<8;j++) acc[j] += w10*b2f(((bf16*)&v)[j]);
        }
        if ((unsigned)(y0+1) < HH && (unsigned)(x0+1) < WW){
            s16x8 v = *(const s16x8*)(vb + ((size_t)((y0+1)*WW+x0+1))*CM + c0);
            #pragma unroll
            for (int j=0;j<8;j++) acc[j] += w11*b2f(((bf16*)&v)[j]);
        }
    }
    s16x8 ov;
    #pragma unroll
    for (int j=0;j<8;j++) ((bf16*)&ov)[j] = __float2bfloat16(acc[j]);
    *(s16x8*)(o + (size_t)pix*CM + c0) = ov;
}

// ---------------- K4b: output proj via MFMA (A=Wout^T, B=o^T) + BN2 + SiLU + residual ----------------
__global__ __launch_bounds__(256) void k4b(
    const bf16* __restrict__ o, const bf16* __restrict__ Wf2, const float* __restrict__ scbi,
    const float* __restrict__ xin, float* __restrict__ out)
{
    __shared__ __align__(16) bf16 Bl[64*136];
    int blk = blockIdx.x;
    int n = blk/49; int p0 = (blk%49)*64;
    int tid = threadIdx.x;
    for (int e = tid; e < 1024; e += 256){
        int row = e>>4, seg = e&15;
        *(s16x8*)&Bl[row*136 + seg*8] = *(const s16x8*)(o + ((size_t)n*HWSZ + p0 + row)*CM + seg*8);
    }
    __syncthreads();
    int lane = tid & 63, w = tid >> 6;
    int col = lane & 15, kq = lane >> 4;
    int co0 = w*64;
    s16x8 af[4][4];
    #pragma unroll
    for (int mt=0;mt<4;mt++)
        #pragma unroll
        for (int kc=0;kc<4;kc++)
            af[mt][kc] = *(const s16x8*)(Wf2 + (((size_t)((co0>>4)+mt)*4 + kc)*64 + lane)*8);
    f32x4 acc[4][4];
    #pragma unroll
    for (int mt=0;mt<4;mt++)
        #pragma unroll
        for (int nt=0;nt<4;nt++)
            acc[mt][nt] = (f32x4){0,0,0,0};
    #pragma unroll
    for (int nt=0;nt<4;nt++){
        s16x8 bfr[4];
        #pragma unroll
        for (int kc=0;kc<4;kc++)
            bfr[kc] = *(const s16x8*)&Bl[(nt*16+col)*136 + kc*32 + kq*8];
        #pragma unroll
        for (int mt=0;mt<4;mt++)
            #pragma unroll
            for (int kc=0;kc<4;kc++)
                acc[mt][nt] = __builtin_amdgcn_mfma_f32_16x16x32_bf16(af[mt][kc], bfr[kc], acc[mt][nt], 0, 0, 0);
    }
    #pragma unroll
    for (int mt=0;mt<4;mt++){
        #pragma unroll
        for (int r=0;r<4;r++){
            int co = co0 + mt*16 + kq*4 + r;
            float sc = scbi[co], bi = scbi[256+co];
            #pragma unroll
            for (int nt=0;nt<4;nt++){
                int px = p0 + nt*16 + col;
                size_t idx = ((size_t)(n*C2 + co))*HWSZ + px;
                float z = acc[mt][nt][r]*sc + bi;
                float sl = z/(1.f+expf(-z));
                out[idx] = sl + xin[idx];
            }
        }
    }
}

extern "C" void kernel_launch(void* const* d_in, const int* in_sizes, int n_in,
                              void* d_out, int out_size, void* d_ws, size_t ws_size,
                              hipStream_t stream)
{
    const float* x    = (const float*)d_in[0];
    const float* wcv1 = (const float*)d_in[1];
    const float* bn1g = (const float*)d_in[2];
    const float* bn1b = (const float*)d_in[3];
    const float* bn1m = (const float*)d_in[4];
    const float* bn1v = (const float*)d_in[5];
    const float* wdw  = (const float*)d_in[6];
    const float* bdw  = (const float*)d_in[7];
    const float* lng  = (const float*)d_in[8];
    const float* lnb  = (const float*)d_in[9];
    const float* winp = (const float*)d_in[10];
    const float* binp = (const float*)d_in[11];
    const float* woff = (const float*)d_in[12];
    const float* boff = (const float*)d_in[13];
    const float* wmsk = (const float*)d_in[14];
    const float* bmsk = (const float*)d_in[15];
    const float* wout = (const float*)d_in[16];
    const float* bout = (const float*)d_in[17];
    const float* bn2g = (const float*)d_in[18];
    const float* bn2b = (const float*)d_in[19];
    const float* bn2m = (const float*)d_in[20];
    const float* bn2v = (const float*)d_in[21];

    unsigned char* base = (unsigned char*)d_ws;
    bf16*  Wf   = (bf16*)(base);                    //   589,824
    bf16*  Wf2  = (bf16*)(base + 589824);           //    65,536
    bf16*  Wf3  = (bf16*)(base + 655360);           //    32,768
    bf16*  Wf4  = (bf16*)(base + 688128);           //    28,672
    float* scbi = (float*)(base + 716800);          //     2,048
    float* wdwT = (float*)(base + 718848);          //     4,608
    bf16*  xp   = (bf16*)(base + 723456);           // 13,778,944 (dead after k1; tb/val alias)
    bf16*  tb   = (bf16*)(base + 723456);           //  6,422,528
    bf16*  val  = (bf16*)(base + 7145984);          //  6,422,528
    bf16*  hb   = (bf16*)(base + 14502400);         //  6,422,528
    float* om   = (float*)(base + 20924928);        // 11,239,424
    bf16*  o    = (bf16*)(base + 32164352);         //  6,422,528 (end 38,586,880)

    hipLaunchKernelGGL(k0pre, dim3(2037), dim3(256), 0, stream,
                       x, wcv1, wout, winp, woff, wmsk, bn2g, bn2b, bn2m, bn2v, bout, wdw,
                       xp, Wf, Wf2, Wf3, Wf4, scbi, wdwT);
    hipLaunchKernelGGL(k1_mfma, dim3(NN*98), dim3(256), 0, stream,
                       xp, Wf, bn1g, bn1b, bn1m, bn1v, hb);
    hipLaunchKernelGGL(k2v, dim3(LL/8), dim3(128), 0, stream,
                       hb, wdwT, bdw, lng, lnb, tb);
    hipLaunchKernelGGL(k3_gemm, dim3(NN*98), dim3(256), 0, stream,
                       hb, tb, Wf3, Wf4, binp, boff, bmsk, val, om);
    hipLaunchKernelGGL(k4a, dim3(LL/8), dim3(128), 0, stream, val, om, o);
    hipLaunchKernelGGL(k4b, dim3(NN*49), dim3(256), 0, stream, o, Wf2, scbi, x, (float*)d_out);
}

// Round 10
// 206.433 us; speedup vs baseline: 1.4238x; 1.1204x over previous
//
#include <hip/hip_runtime.h>
#include <hip/hip_bf16.h>

typedef __hip_bfloat16 bf16;
typedef float f32x4 __attribute__((ext_vector_type(4)));
typedef short s16x8 __attribute__((ext_vector_type(8)));

#define NN 8
#define HH 56
#define WW 56
#define C1 256
#define CM 128
#define C2 256
#define GG 4
#define K2K 9
#define HWSZ (HH*WW)            // 3136
#define LL (NN*HWSZ)            // 25088
#define EPSF 1e-5f
#define XP_H 58
#define XP_W 58

__device__ __forceinline__ float b2f(bf16 v){ return __bfloat162float(v); }

// ---------------- K0pre: input pad/transpose + all weight repacks in ONE launch ----------------
__global__ __launch_bounds__(256) void k0pre(
    const float* __restrict__ x, const float* __restrict__ w,
    const float* __restrict__ wout, const float* __restrict__ winp,
    const float* __restrict__ woff, const float* __restrict__ wmsk,
    const float* __restrict__ g2, const float* __restrict__ bb2,
    const float* __restrict__ m2, const float* __restrict__ v2,
    const float* __restrict__ bout, const float* __restrict__ wdw,
    bf16* __restrict__ xp, bf16* __restrict__ Wf, bf16* __restrict__ Wf2,
    bf16* __restrict__ Wf3, bf16* __restrict__ Wf4,
    float* __restrict__ scbi, float* __restrict__ wdwT)
{
    int bidg = blockIdx.x;
    if (bidg < 1856){
        __shared__ float lds[64][57];
        int n = bidg / 232; int rem = bidg % 232;
        int yp = rem >> 2; int ci0 = (rem & 3) << 6;
        int tid = threadIdx.x;
        bool interior = (yp >= 1 && yp <= 56);
        if (interior){
            int y = yp - 1;
            for (int e = tid; e < 64*56; e += 256){
                int ci = e / 56, xx = e - (e/56)*56;
                lds[ci][xx] = x[((size_t)((n*C1 + ci0 + ci)*HH) + y)*WW + xx];
            }
            __syncthreads();
        }
        for (int g = tid; g < 464; g += 256){
            int pxp = g >> 3, cig = (g & 7) << 3;
            s16x8 v;
            if (!interior || pxp == 0 || pxp == 57){
                #pragma unroll
                for (int j=0;j<8;j++) ((bf16*)&v)[j] = __float2bfloat16(0.f);
            } else {
                #pragma unroll
                for (int j=0;j<8;j++) ((bf16*)&v)[j] = __float2bfloat16(lds[cig+j][pxp-1]);
            }
            *(s16x8*)(xp + ((size_t)(n*XP_H + yp)*XP_W + pxp)*C1 + ci0 + cig) = v;
        }
        return;
    }
    if (bidg < 2000){
        int tlin = (bidg-1856)*256 + threadIdx.x;   // 36864
        int kt  = tlin >> 9;
        int rem = tlin & 511;
        int nt  = rem >> 6;
        int lane = rem & 63;
        int co = nt*16 + (lane & 15);
        int kbase = kt*32 + (lane >> 4)*8;
        bf16* dst = Wf + (size_t)tlin*8;
        #pragma unroll
        for (int j = 0; j < 8; j++){
            int k = kbase + j;
            int tap = k >> 8;
            int ci  = k & 255;
            dst[j] = __float2bfloat16(w[((size_t)co*C1 + ci)*9 + tap]);
        }
        return;
    }
    int t = (bidg-2000)*256 + threadIdx.x;
    if (t < 4096){          // Wf2: A-frag wout^T
        int lane = t & 63; int kc = (t>>6)&3; int mt = t>>8;
        int co = mt*16 + (lane&15); int k0 = kc*32 + (lane>>4)*8;
        bf16* d = Wf2 + (size_t)t*8;
        #pragma unroll
        for (int j=0;j<8;j++) d[j] = __float2bfloat16(wout[(size_t)(k0+j)*C2 + co]);
    } else if (t < 6144){   // Wf3: B-frag winp
        int u = t - 4096; int lane = u&63; int kc=(u>>6)&3; int nt=u>>8;
        int co = nt*16+(lane&15); int k0 = kc*32+(lane>>4)*8;
        bf16* d = Wf3 + (size_t)u*8;
        #pragma unroll
        for (int j=0;j<8;j++) d[j] = __float2bfloat16(winp[(size_t)(k0+j)*CM + co]);
    } else if (t < 7936){   // Wf4: B-frag [woff|wmsk|0]
        int u = t - 6144; int lane=u&63; int kc=(u>>6)&3; int nt=u>>8;
        int nn2 = nt*16+(lane&15); int k0 = kc*32+(lane>>4)*8;
        bf16* d = Wf4 + (size_t)u*8;
        #pragma unroll
        for (int j=0;j<8;j++){
            int k = k0+j; float v = 0.f;
            if (nn2 < 72) v = woff[(size_t)k*72 + nn2];
            else if (nn2 < 108) v = wmsk[(size_t)k*36 + (nn2-72)];
            d[j] = __float2bfloat16(v);
        }
    } else if (t < 8192){
        int co = t - 7936;
        float sc = g2[co]*rsqrtf(v2[co]+EPSF);
        scbi[co] = sc;
        scbi[256+co] = bb2[co] - m2[co]*sc + bout[co]*sc;
    } else if (t < 8192 + 9*CM){
        int u = t - 8192;
        int tap = u >> 7, c = u & 127;
        wdwT[tap*CM + c] = wdw[c*9 + tap];
    }
}

// ---------------- K1: MFMA conv, BK=64, A+B both via global_load_lds, wave-tile 32x32 ----------------
__device__ __forceinline__ void stageB(const bf16* __restrict__ Wf, int s32, bf16* buf, int w, int lane){
    const bf16* g = Wf + ((size_t)s32 << 12) + (w << 10) + lane*8;
    bf16* l = buf + (w << 10);
    __builtin_amdgcn_global_load_lds((const __attribute__((address_space(1))) void*)g,
                                     (__attribute__((address_space(3))) void*)l, 16, 0, 0);
    __builtin_amdgcn_global_load_lds((const __attribute__((address_space(1))) void*)(g + 512),
                                     (__attribute__((address_space(3))) void*)(l + 512), 16, 0, 0);
}

__global__ __launch_bounds__(256) void k1_mfma(
    const bf16* __restrict__ xp, const bf16* __restrict__ Wf,
    const float* __restrict__ bg, const float* __restrict__ bb,
    const float* __restrict__ bm, const float* __restrict__ bv,
    bf16* __restrict__ hb)
{
    __shared__ __align__(16) bf16 Bbuf[2][8192];   // 2 x 16 KB
    __shared__ __align__(16) bf16 Abuf[2][2048];   // 2 x 4 KB, swizzled [p*8 + (cg-p)&7]
    int bid = blockIdx.x;               // 784 = 8*98
    int n = bid/98, p0 = (bid%98)*32;
    int tid = threadIdx.x, lane = tid & 63;
    int w  = tid >> 6;                  // N-quarter: co = w*32 ..
    int col = lane & 15, kq = lane >> 4;

    // A staging source: thread t stages row p=t>>3 (local), swizzled global chunk g=((t&7)+p)&7
    int pS = tid >> 3;
    int gS = ((tid & 7) + pS) & 7;
    {
        // silence unused warnings pattern
    }
    int pxS = p0 + pS;
    int yS = pxS/WW, xS = pxS - yS*WW;
    long sbase = ((long)((n*XP_H + yS + 1)*XP_W) + (xS + 1))*C1 + gS*8;

    // A-frag LDS slot swizzle offsets (independent of mi since 16 ≡ 0 mod 8)
    int sw0 = (kq - col) & 7;           // ks=0
    int sw1 = (kq + 4 - col) & 7;       // ks=1

    f32x4 acc[2][2];
    #pragma unroll
    for (int mi=0;mi<2;mi++)
        #pragma unroll
        for (int ct=0;ct<2;ct++) acc[mi][ct] = (f32x4){0,0,0,0};

    // stage chunk s (BK=64) into buffer b
    #define STAGE(s, b) do { \
        stageB(Wf, 2*(s),   &Bbuf[b][0],    w, lane); \
        stageB(Wf, 2*(s)+1, &Bbuf[b][4096], w, lane); \
        int tap_ = (s) >> 2; int dy_ = tap_/3, dx_ = tap_ - dy_*3; \
        int ci0_ = ((s) & 3) << 6; \
        const bf16* ga_ = xp + sbase + ((dy_-1)*XP_W + (dx_-1))*C1 + ci0_; \
        __builtin_amdgcn_global_load_lds((const __attribute__((address_space(1))) void*)ga_, \
            (__attribute__((address_space(3))) void*)(&Abuf[b][0] + (w << 9)), 16, 0, 0); \
    } while(0)

    STAGE(0, 0);
    __syncthreads();

    for (int s = 0; s < 36; ++s){
        int b = s & 1;
        if (s + 1 < 36) STAGE(s+1, b^1);
        #pragma unroll
        for (int ks = 0; ks < 2; ++ks){
            int swk = ks ? sw1 : sw0;
            s16x8 a0 = *(const s16x8*)&Abuf[b][ (col*8      + swk) * 8 ];
            s16x8 a1 = *(const s16x8*)&Abuf[b][ ((16+col)*8 + swk) * 8 ];
            s16x8 b0 = *(const s16x8*)&Bbuf[b][ ks*4096 + (w*2+0)*512 + lane*8 ];
            s16x8 b1 = *(const s16x8*)&Bbuf[b][ ks*4096 + (w*2+1)*512 + lane*8 ];
            acc[0][0] = __builtin_amdgcn_mfma_f32_16x16x32_bf16(a0, b0, acc[0][0], 0, 0, 0);
            acc[0][1] = __builtin_amdgcn_mfma_f32_16x16x32_bf16(a0, b1, acc[0][1], 0, 0, 0);
            acc[1][0] = __builtin_amdgcn_mfma_f32_16x16x32_bf16(a1, b0, acc[1][0], 0, 0, 0);
            acc[1][1] = __builtin_amdgcn_mfma_f32_16x16x32_bf16(a1, b1, acc[1][1], 0, 0, 0);
        }
        __syncthreads();
    }
    #undef STAGE

    // epilogue: C layout col->co-col, kq*4+r -> px-row; co = w*32 + ct*16 + col
    #pragma unroll
    for (int ct = 0; ct < 2; ++ct){
        int co = w*32 + ct*16 + col;
        float sc = bg[co] * rsqrtf(bv[co] + EPSF);
        float bi = bb[co] - bm[co]*sc;
        #pragma unroll
        for (int mi = 0; mi < 2; ++mi){
            #pragma unroll
            for (int r = 0; r < 4; ++r){
                int px = p0 + mi*16 + kq*4 + r;
                float z = acc[mi][ct][r]*sc + bi;
                float sl = z / (1.f + expf(-z));
                hb[((size_t)n*HWSZ + px)*CM + co] = __float2bfloat16(sl);
            }
        }
    }
}

// ---------------- K2: depthwise 3x3 + LN + GELU, 8 pixels/block (high TLP) ----------------
__global__ __launch_bounds__(128) void k2v(
    const bf16* __restrict__ hb, const float* __restrict__ wdwT, const float* __restrict__ bdw,
    const float* __restrict__ lng, const float* __restrict__ lnb, bf16* __restrict__ tb)
{
    int t = threadIdx.x;
    int p = t >> 4, s = t & 15;
    int pix = blockIdx.x*8 + p;
    int n = pix / HWSZ, rem = pix % HWSZ;
    int y = rem / WW, xq = rem % WW;
    int c0 = s*8;
    const bf16* hbase = hb + (size_t)n*HWSZ*CM;
    float acc[8];
    {
        float4 b0 = *(const float4*)(bdw + c0);
        float4 b1 = *(const float4*)(bdw + c0 + 4);
        acc[0]=b0.x; acc[1]=b0.y; acc[2]=b0.z; acc[3]=b0.w;
        acc[4]=b1.x; acc[5]=b1.y; acc[6]=b1.z; acc[7]=b1.w;
    }
    #pragma unroll
    for (int tap=0; tap<9; tap++){
        int dy=tap/3, dx=tap%3;
        int yy=y+dy-1, xx=xq+dx-1;
        if ((unsigned)yy < HH && (unsigned)xx < WW){
            s16x8 v = *(const s16x8*)(hbase + ((size_t)(yy*WW+xx))*CM + c0);
            float4 w0 = *(const float4*)(wdwT + tap*CM + c0);
            float4 w1 = *(const float4*)(wdwT + tap*CM + c0 + 4);
            float wv[8] = {w0.x,w0.y,w0.z,w0.w,w1.x,w1.y,w1.z,w1.w};
            #pragma unroll
            for (int j=0;j<8;j++)
                acc[j] += b2f(((bf16*)&v)[j]) * wv[j];
        }
    }
    float s1=0.f, s2=0.f;
    #pragma unroll
    for (int j=0;j<8;j++){ s1 += acc[j]; s2 += acc[j]*acc[j]; }
    #pragma unroll
    for (int off=1; off<16; off<<=1){
        s1 += __shfl_xor(s1, off);
        s2 += __shfl_xor(s2, off);
    }
    float mean = s1*(1.f/CM);
    float var  = fmaxf(s2*(1.f/CM) - mean*mean, 0.f);
    float inv  = rsqrtf(var + EPSF);
    float4 g0 = *(const float4*)(lng + c0); float4 g1 = *(const float4*)(lng + c0+4);
    float4 q0 = *(const float4*)(lnb + c0); float4 q1 = *(const float4*)(lnb + c0+4);
    float gv[8]={g0.x,g0.y,g0.z,g0.w,g1.x,g1.y,g1.z,g1.w};
    float qv[8]={q0.x,q0.y,q0.z,q0.w,q1.x,q1.y,q1.z,q1.w};
    s16x8 ov;
    #pragma unroll
    for (int j=0;j<8;j++){
        float z = (acc[j]-mean)*inv*gv[j] + qv[j];
        float gl = 0.5f*z*(1.f + erff(z*0.70710678118654752f));
        ((bf16*)&ov)[j] = __float2bfloat16(gl);
    }
    *(s16x8*)(tb + (size_t)pix*CM + c0) = ov;
}

// ---------------- K3: MFMA GEMMs, M=32 tiles (784 blocks for TLP) ----------------
__global__ __launch_bounds__(256) void k3_gemm(
    const bf16* __restrict__ hb, const bf16* __restrict__ tb,
    const bf16* __restrict__ Wf3, const bf16* __restrict__ Wf4,
    const float* __restrict__ binp, const float* __restrict__ boff, const float* __restrict__ bmsk,
    bf16* __restrict__ val, float* __restrict__ om)
{
    __shared__ __align__(16) bf16 Ah[32*136];
    __shared__ __align__(16) bf16 At[32*136];
    int blk = blockIdx.x;               // 784 = 8*98
    int n = blk/98; int p0 = (blk%98)*32;
    size_t pixbase = (size_t)n*HWSZ + p0;
    int tid = threadIdx.x;
    for (int e = tid; e < 512; e += 256){
        int row = e>>4, seg = e&15;
        *(s16x8*)&Ah[row*136 + seg*8] = *(const s16x8*)(hb + (pixbase+row)*CM + seg*8);
        *(s16x8*)&At[row*136 + seg*8] = *(const s16x8*)(tb + (pixbase+row)*CM + seg*8);
    }
    __syncthreads();
    int lane = tid & 63, w = tid >> 6;
    int col = lane & 15, kq = lane >> 4;
    int mt = w & 1, wn = w >> 1;       // mt: M-tile, wn: N-half
    s16x8 a0[4], a1[4];
    #pragma unroll
    for (int kc=0;kc<4;kc++){
        a0[kc] = *(const s16x8*)&Ah[(mt*16+col)*136 + kc*32 + kq*8];
        a1[kc] = *(const s16x8*)&At[(mt*16+col)*136 + kc*32 + kq*8];
    }
    int pxo = p0 + mt*16 + kq*4;
    #pragma unroll
    for (int nti=0; nti<4; nti++){
        int nt = wn*4 + nti;
        f32x4 acc = {0,0,0,0};
        #pragma unroll
        for (int kc=0;kc<4;kc++){
            s16x8 b = *(const s16x8*)(Wf3 + ((size_t)(nt*4+kc)*64 + lane)*8);
            acc = __builtin_amdgcn_mfma_f32_16x16x32_bf16(a0[kc], b, acc, 0, 0, 0);
        }
        int co = nt*16 + col;
        float bia = binp[co];
        #pragma unroll
        for (int r=0;r<4;r++)
            val[((size_t)n*HWSZ + pxo + r)*CM + co] = __float2bfloat16(acc[r] + bia);
    }
    #pragma unroll
    for (int nti=0; nti<4; nti++){
        int nt = wn*4 + nti;
        if (nt < 7){
            f32x4 acc = {0,0,0,0};
            #pragma unroll
            for (int kc=0;kc<4;kc++){
                s16x8 b = *(const s16x8*)(Wf4 + ((size_t)(nt*4+kc)*64 + lane)*8);
                acc = __builtin_amdgcn_mfma_f32_16x16x32_bf16(a1[kc], b, acc, 0, 0, 0);
            }
            int nn2 = nt*16 + col;
            float bia = (nn2<72) ? boff[nn2] : (nn2<108 ? bmsk[nn2-72] : 0.f);
            #pragma unroll
            for (int r=0;r<4;r++)
                om[((size_t)n*HWSZ + pxo + r)*112 + nn2] = acc[r] + bia;
        }
    }
}

// ---------------- K4a: softmax + DCNv3 bilinear gather, 8 pixels/block, 16B loads ----------------
__global__ __launch_bounds__(128) void k4a(
    const bf16* __restrict__ valb, const float* __restrict__ om, bf16* __restrict__ o)
{
    __shared__ float omb[8][112];
    __shared__ float mk[8][36];
    int t = threadIdx.x;
    int pix0 = blockIdx.x*8;
    for (int e = t; e < 8*112; e += 128){
        int p = e / 112, q = e - (e/112)*112;
        omb[p][q] = om[(size_t)(pix0+p)*112 + q];
    }
    __syncthreads();
    if (t < 32){
        int p = t >> 2, g = t & 3;
        float mx = omb[p][72+g*9];
        #pragma unroll
        for (int j=1;j<9;j++) mx = fmaxf(mx, omb[p][72+g*9+j]);
        float sum=0.f; float e9[9];
        #pragma unroll
        for (int j=0;j<9;j++){ e9[j] = expf(omb[p][72+g*9+j]-mx); sum += e9[j]; }
        float inv = 1.f/sum;
        #pragma unroll
        for (int j=0;j<9;j++) mk[p][g*9+j] = e9[j]*inv;
    }
    __syncthreads();
    int p = t >> 4, s = t & 15;
    int g = s >> 2;
    int c0 = s*8;
    int pix = pix0 + p;
    int n = pix / HWSZ, rem = pix % HWSZ;
    int y = rem / WW, xq = rem % WW;
    const bf16* vb = valb + (size_t)n*HWSZ*CM;
    float acc[8] = {0,0,0,0,0,0,0,0};
    #pragma unroll
    for (int k=0;k<9;k++){
        float oxv = omb[p][g*18 + k*2];
        float oyv = omb[p][g*18 + k*2 + 1];
        float sx = (float)xq + (float)(k/3) - 1.f + oxv;
        float sy = (float)y  + (float)(k%3) - 1.f + oyv;
        float x0f = floorf(sx), y0f = floorf(sy);
        float fx = sx - x0f, fy = sy - y0f;
        int x0 = (int)x0f, y0 = (int)y0f;
        float mw = mk[p][g*9+k];
        float w00 = (1.f-fy)*(1.f-fx)*mw;
        float w01 = (1.f-fy)*fx*mw;
        float w10 = fy*(1.f-fx)*mw;
        float w11 = fy*fx*mw;
        if ((unsigned)y0 < HH && (unsigned)x0 < WW){
            s16x8 v = *(const s16x8*)(vb + ((size_t)(y0*WW+x0))*CM + c0);
            #pragma unroll
            for (int j=0;j<8;j++) acc[j] += w00*b2f(((bf16*)&v)[j]);
        }
        if ((unsigned)y0 < HH && (unsigned)(x0+1) < WW){
            s16x8 v = *(const s16x8*)(vb + ((size_t)(y0*WW+x0+1))*CM + c0);
            #pragma unroll
            for (int j=0;j<8;j++) acc[j] += w01*b2f(((bf16*)&v)[j]);
        }
        if ((unsigned)(y0+1) < HH && (unsigned)x0 < WW){
            s16x8 v = *(const s16x8*)(vb + ((size_t)((y0+1)*WW+x0))*CM + c0);
            #pragma unroll
            for (int j=0;j<8;j++) acc[j] += w10*b2f(((bf16*)&v)[j]);
        }
        if ((unsigned)(y0+1) < HH && (unsigned)(x0+1) < WW){
            s16x8 v = *(const s16x8*)(vb + ((size_t)((y0+1)*WW+x0+1))*CM + c0);
            #pragma unroll
            for (int j=0;j<8;j++) acc[j] += w11*b2f(((bf16*)&v)[j]);
        }
    }
    s16x8 ov;
    #pragma unroll
    for (int j=0;j<8;j++) ((bf16*)&ov)[j] = __float2bfloat16(acc[j]);
    *(s16x8*)(o + (size_t)pix*CM + c0) = ov;
}

// ---------------- K4b: output proj via MFMA (A=Wout^T, B=o^T) + BN2 + SiLU + residual ----------------
__global__ __launch_bounds__(256) void k4b(
    const bf16* __restrict__ o, const bf16* __restrict__ Wf2, const float* __restrict__ scbi,
    const float* __restrict__ xin, float* __restrict__ out)
{
    __shared__ __align__(16) bf16 Bl[64*136];
    int blk = blockIdx.x;
    int n = blk/49; int p0 = (blk%49)*64;
    int tid = threadIdx.x;
    for (int e = tid; e < 1024; e += 256){
        int row = e>>4, seg = e&15;
        *(s16x8*)&Bl[row*136 + seg*8] = *(const s16x8*)(o + ((size_t)n*HWSZ + p0 + row)*CM + seg*8);
    }
    __syncthreads();
    int lane = tid & 63, w = tid >> 6;
    int col = lane & 15, kq = lane >> 4;
    int co0 = w*64;
    s16x8 af[4][4];
    #pragma unroll
    for (int mt=0;mt<4;mt++)
        #pragma unroll
        for (int kc=0;kc<4;kc++)
            af[mt][kc] = *(const s16x8*)(Wf2 + (((size_t)((co0>>4)+mt)*4 + kc)*64 + lane)*8);
    f32x4 acc[4][4];
    #pragma unroll
    for (int mt=0;mt<4;mt++)
        #pragma unroll
        for (int nt=0;nt<4;nt++)
            acc[mt][nt] = (f32x4){0,0,0,0};
    #pragma unroll
    for (int nt=0;nt<4;nt++){
        s16x8 bfr[4];
        #pragma unroll
        for (int kc=0;kc<4;kc++)
            bfr[kc] = *(const s16x8*)&Bl[(nt*16+col)*136 + kc*32 + kq*8];
        #pragma unroll
        for (int mt=0;mt<4;mt++)
            #pragma unroll
            for (int kc=0;kc<4;kc++)
                acc[mt][nt] = __builtin_amdgcn_mfma_f32_16x16x32_bf16(af[mt][kc], bfr[kc], acc[mt][nt], 0, 0, 0);
    }
    #pragma unroll
    for (int mt=0;mt<4;mt++){
        #pragma unroll
        for (int r=0;r<4;r++){
            int co = co0 + mt*16 + kq*4 + r;
            float sc = scbi[co], bi = scbi[256+co];
            #pragma unroll
            for (int nt=0;nt<4;nt++){
                int px = p0 + nt*16 + col;
                size_t idx = ((size_t)(n*C2 + co))*HWSZ + px;
                float z = acc[mt][nt][r]*sc + bi;
                float sl = z/(1.f+expf(-z));
                out[idx] = sl + xin[idx];
            }
        }
    }
}

extern "C" void kernel_launch(void* const* d_in, const int* in_sizes, int n_in,
                              void* d_out, int out_size, void* d_ws, size_t ws_size,
                              hipStream_t stream)
{
    const float* x    = (const float*)d_in[0];
    const float* wcv1 = (const float*)d_in[1];
    const float* bn1g = (const float*)d_in[2];
    const float* bn1b = (const float*)d_in[3];
    const float* bn1m = (const float*)d_in[4];
    const float* bn1v = (const float*)d_in[5];
    const float* wdw  = (const float*)d_in[6];
    const float* bdw  = (const float*)d_in[7];
    const float* lng  = (const float*)d_in[8];
    const float* lnb  = (const float*)d_in[9];
    const float* winp = (const float*)d_in[10];
    const float* binp = (const float*)d_in[11];
    const float* woff = (const float*)d_in[12];
    const float* boff = (const float*)d_in[13];
    const float* wmsk = (const float*)d_in[14];
    const float* bmsk = (const float*)d_in[15];
    const float* wout = (const float*)d_in[16];
    const float* bout = (const float*)d_in[17];
    const float* bn2g = (const float*)d_in[18];
    const float* bn2b = (const float*)d_in[19];
    const float* bn2m = (const float*)d_in[20];
    const float* bn2v = (const float*)d_in[21];

    unsigned char* base = (unsigned char*)d_ws;
    bf16*  Wf   = (bf16*)(base);                    //   589,824
    bf16*  Wf2  = (bf16*)(base + 589824);           //    65,536
    bf16*  Wf3  = (bf16*)(base + 655360);           //    32,768
    bf16*  Wf4  = (bf16*)(base + 688128);           //    28,672
    float* scbi = (float*)(base + 716800);          //     2,048
    float* wdwT = (float*)(base + 718848);          //     4,608
    bf16*  xp   = (bf16*)(base + 723456);           // 13,778,944 (dead after k1; tb/val alias)
    bf16*  tb   = (bf16*)(base + 723456);           //  6,422,528
    bf16*  val  = (bf16*)(base + 7145984);          //  6,422,528
    bf16*  hb   = (bf16*)(base + 14502400);         //  6,422,528
    float* om   = (float*)(base + 20924928);        // 11,239,424
    bf16*  o    = (bf16*)(base + 32164352);         //  6,422,528 (end 38,586,880)

    hipLaunchKernelGGL(k0pre, dim3(2037), dim3(256), 0, stream,
                       x, wcv1, wout, winp, woff, wmsk, bn2g, bn2b, bn2m, bn2v, bout, wdw,
                       xp, Wf, Wf2, Wf3, Wf4, scbi, wdwT);
    hipLaunchKernelGGL(k1_mfma, dim3(NN*98), dim3(256), 0, stream,
                       xp, Wf, bn1g, bn1b, bn1m, bn1v, hb);
    hipLaunchKernelGGL(k2v, dim3(LL/8), dim3(128), 0, stream,
                       hb, wdwT, bdw, lng, lnb, tb);
    hipLaunchKernelGGL(k3_gemm, dim3(NN*98), dim3(256), 0, stream,
                       hb, tb, Wf3, Wf4, binp, boff, bmsk, val, om);
    hipLaunchKernelGGL(k4a, dim3(LL/8), dim3(128), 0, stream, val, om, o);
    hipLaunchKernelGGL(k4b, dim3(NN*49), dim3(256), 0, stream, o, Wf2, scbi, x, (float*)d_out);
}